// Round 15
// baseline (790.857 us; speedup 1.0000x reference)
//
#include <hip/hip_runtime.h>
#include <hip/hip_bf16.h>
#include <math.h>

typedef __hip_bfloat16 bf16;
typedef __attribute__((ext_vector_type(8))) short s8v;   // 8 bf16 (4 VGPRs)
typedef __attribute__((ext_vector_type(4))) float f4v;   // MFMA acc

// ---------------- problem constants ----------------
#define B_   2
#define N_   4
#define H_   256
#define W_   256
#define P_   2048
#define CHF  255
#define BP_  (B_*P_)          // 4096
#define ROWS_IA (BP_*N_)      // 16384
#define NPIX 16384            // 128*128
#define CONV_M (8*NPIX)       // 131072
#define SPLITS 4              // attention KV split (KVBLK=64)

// ---------------- static scratch ----------------
constexpr size_t SZ_X      = (size_t)8*7*65536;
constexpr size_t SZ_EXT    = (size_t)8*NPIX*256;
constexpr size_t PS_CAT    = (size_t)ROWS_IA*288;
constexpr size_t PS_256    = (size_t)ROWS_IA*256;
constexpr size_t PS_QKV    = (size_t)ROWS_IA*768;
constexpr size_t PS_FF     = (size_t)ROWS_IA*1024;
constexpr size_t PS_PROJ   = (size_t)ROWS_IA*384;
constexpr size_t PS_384    = (size_t)BP_*384;
constexpr size_t PS_QKVP   = (size_t)BP_*1152;
constexpr size_t PS_FF2    = (size_t)BP_*1024;
constexpr size_t PS_PAT    = (size_t)CONV_M*64;
constexpr size_t SZ_WT     = 2347008;
constexpr size_t PS_VT     = (size_t)2*8*48*2048;   // shorts per VT plane

constexpr size_t OFF_X      = 0;
constexpr size_t OFF_EXTA   = OFF_X      + SZ_X;
constexpr size_t OFF_EXTB   = OFF_EXTA   + SZ_EXT;
constexpr size_t OFF_CAT    = OFF_EXTB   + SZ_EXT;
constexpr size_t OFF_TOK    = OFF_CAT    + PS_CAT;
constexpr size_t OFF_QKV    = OFF_TOK    + PS_256;
constexpr size_t OFF_ATTNO  = OFF_QKV    + PS_QKV;
constexpr size_t OFF_TMP256 = OFF_ATTNO  + PS_256;
constexpr size_t OFF_Y1     = OFF_TMP256 + PS_256;
constexpr size_t OFF_FF     = OFF_Y1     + PS_256;
constexpr size_t OFF_TMP256B= OFF_FF     + PS_FF;
constexpr size_t OFF_Y2     = OFF_TMP256B+ PS_256;
constexpr size_t OFF_PROJ   = OFF_Y2     + PS_256;
constexpr size_t OFF_Z      = OFF_PROJ   + PS_PROJ;
constexpr size_t OFF_QKVP   = OFF_Z      + PS_384;
constexpr size_t OFF_ATTNP  = OFF_QKVP   + PS_QKVP;
constexpr size_t OFF_TMP384 = OFF_ATTNP  + PS_384;
constexpr size_t OFF_Z2     = OFF_TMP384 + PS_384;
constexpr size_t OFF_FFB2   = OFF_Z2     + PS_384;
constexpr size_t OFF_TMP384B= OFF_FFB2   + PS_FF2;
constexpr size_t OFF_GLB    = OFF_TMP384B+ PS_384;
constexpr size_t OFF_RAW5   = OFF_GLB    + PS_384;
constexpr size_t OFF_WM     = OFF_RAW5   + (size_t)BP_*5;
constexpr size_t OFF_FLAG   = OFF_WM     + 2*65536;
constexpr size_t OFF_WTB    = OFF_FLAG   + 16;
constexpr size_t OFF_PO     = OFF_WTB    + SZ_WT;
constexpr size_t OFF_PM     = OFF_PO     + (size_t)SPLITS*BP_*384;
constexpr size_t OFF_PL     = OFF_PM     + (size_t)SPLITS*BP_*8;
constexpr size_t OFF_VT     = OFF_PL     + (size_t)SPLITS*BP_*8;
constexpr size_t N_FLOATS   = OFF_VT     + PS_VT;

__device__ __align__(256) float g_scratch[N_FLOATS];

constexpr size_t WT_LO_OFF   = 2330624;
constexpr size_t WT_CONV_HI  = 4661248;
constexpr size_t WT_CONV_LO  = WT_CONV_HI + 16384;

__constant__ float GW[11] = {
  0.398942278f, 0.241970724f, 0.0539909665f, 0.00443184841f,
  1.33830226e-4f, 1.48671951e-6f, 6.07588285e-9f, 9.13472041e-12f,
  5.05227108e-15f, 1.02797736e-18f, 7.69459863e-23f };

// ---------------- helpers ----------------
__device__ __forceinline__ float ldin(const void* p, size_t i, int f32) {
  return f32 ? ((const float*)p)[i] : __bfloat162float(((const bf16*)p)[i]);
}
__device__ __forceinline__ void stout(void* p, size_t i, float v, int f32) {
  if (f32) ((float*)p)[i] = v;
  else     ((bf16*)p)[i]  = __float2bfloat16(v);
}
__device__ __forceinline__ float bs2f(short s) {
  bf16 h = *reinterpret_cast<bf16*>(&s);
  return __bfloat162float(h);
}
__device__ __forceinline__ void splitbf(float f, short& hi, short& lo) {
  bf16 h = __float2bfloat16(f);
  float hf = __bfloat162float(h);
  bf16 l = __float2bfloat16(f - hf);
  hi = *reinterpret_cast<short*>(&h);
  lo = *reinterpret_cast<short*>(&l);
}
// async global->LDS 16B copy (dest must be wave-uniform base + lane*16, which
// our tid-linear mapping satisfies)
__device__ __forceinline__ void gl16(const short* g, short* l) {
  __builtin_amdgcn_global_load_lds(
      (const __attribute__((address_space(1))) void*)g,
      (__attribute__((address_space(3))) void*)l, 16, 0, 0);
}

__global__ void probe_k(const unsigned int* __restrict__ m, int* __restrict__ flag)
{
  if (threadIdx.x == 0 && blockIdx.x == 0)
    *flag = (m[0] == 0x3F800000u) ? 1 : 0;
}

// ---------------- stage 1 ----------------
__global__ __launch_bounds__(256) void build_x_k(const void* __restrict__ polar,
    const void* __restrict__ mask, const void* __restrict__ pprop,
    const int* __restrict__ flagp, float* __restrict__ x)
{
  int f32 = *flagp;
  int t = blockIdx.x*256 + threadIdx.x;
  if (t >= (int)SZ_X) return;
  int pix = t & 65535;
  int c   = (t >> 16) % 7;
  int img = t / (7*65536);
  int b = img >> 2, n = img & 3;
  float mv = ldin(mask, (b<<16) + pix, f32);
  float v;
  if (c < 4)       v = ldin(polar, (((size_t)(b*4+n)*4 + c)<<16) + pix, f32) * mv;
  else if (c == 4) v = mv;
  else             v = ldin(pprop, (((size_t)(b*2 + (c-5)))<<16) + pix, f32) * mv;
  x[t] = v;
}

__global__ __launch_bounds__(256) void im2col_k(const float* __restrict__ x,
    short* __restrict__ ph, short* __restrict__ pl_)
{
  int t = blockIdx.x*256 + threadIdx.x;
  if (t >= (int)PS_PAT) return;
  int k = t & 63, row = t >> 6;
  int pix = row & (NPIX-1), img = row >> 14;
  int oy = pix >> 7, ox = pix & 127;
  float v = 0.f;
  if (k < 63) {
    int ic = k / 9, r = k - ic*9;
    int ky = r / 3, kx = r - ky*3;
    int iy = 2*oy + ky, ix = 2*ox + kx;
    if (iy <= 255 && ix <= 255)
      v = x[((size_t)img*7 + ic)*65536 + iy*256 + ix];
  }
  short hh, ll; splitbf(v, hh, ll);
  ph[t] = hh; pl_[t] = ll;
}

__global__ __launch_bounds__(256) void wt_conv_k(const void* __restrict__ w,
    short* __restrict__ dhi, short* __restrict__ dlo, const int* __restrict__ flagp)
{
  int f32 = *flagp;
  int t = blockIdx.x*256 + threadIdx.x;
  if (t >= 256*64) return;
  int oc = t >> 6, k = t & 63;
  short hi = 0, lo = 0;
  if (oc < 255 && k < 63) splitbf(ldin(w, oc*63 + k, f32), hi, lo);
  dhi[t] = hi; dlo[t] = lo;
}

// ---------------- LDS-tiled separable gauss, radius 6 ----------------
template<int VERT>
__global__ __launch_bounds__(256) void gauss2_k(const float* __restrict__ in, float* __restrict__ out)
{
  __shared__ float4 S[128][16];
  int bid = blockIdx.x;
  int chunk = bid & 3;
  int fixed = (bid >> 2) & 127;
  int img = bid >> 9;
  int tid = threadIdx.x;
  int cg = tid & 15;
  int t0 = tid >> 4;
  size_t base = ((size_t)img << 22) + chunk*64 + cg*4;

  #pragma unroll
  for (int tt = t0; tt < 128; tt += 16) {
    int pix = VERT ? ((tt << 7) | fixed) : ((fixed << 7) | tt);
    S[tt][cg] = *(const float4*)(in + base + ((size_t)pix << 8));
  }
  __syncthreads();

  #pragma unroll
  for (int tt = t0; tt < 128; tt += 16) {
    float4 c = S[tt][cg];
    float ax = GW[0]*c.x, ay = GW[0]*c.y, az = GW[0]*c.z, aw = GW[0]*c.w;
    #pragma unroll
    for (int j = 1; j <= 6; ++j) {
      float4 a = {0.f,0.f,0.f,0.f}, b = {0.f,0.f,0.f,0.f};
      if (tt - j >= 0)   a = S[tt - j][cg];
      if (tt + j <= 127) b = S[tt + j][cg];
      float w = GW[j];
      ax += w*(a.x + b.x); ay += w*(a.y + b.y);
      az += w*(a.z + b.z); aw += w*(a.w + b.w);
    }
    int pix = VERT ? ((tt << 7) | fixed) : ((fixed << 7) | tt);
    float4 r; r.x = ax; r.y = ay; r.z = az; r.w = aw;
    *(float4*)(out + base + ((size_t)pix << 8)) = r;
  }
}

// bilinear sample + gather -> cat split planes (stride 288, pad zeroed)
__global__ __launch_bounds__(256) void sample_k(const float* __restrict__ ext,
    const void* __restrict__ polar, const void* __restrict__ mask,
    const int* __restrict__ ids, const int* __restrict__ flagp,
    short* __restrict__ cath, short* __restrict__ catl)
{
  int f32 = *flagp;
  int t = blockIdx.x*256 + threadIdx.x;
  if (t >= (int)PS_CAT) return;
  int ch = t % 288;
  if (ch >= 259) { cath[t] = 0; catl[t] = 0; return; }
  int n  = (t / 288) & 3;
  int bp = t / (288*4);
  int b = bp >> 11;
  int id = ids[bp];
  int row = id >> 8, col = id & 255;
  float out;
  if (ch < 255) {
    float gx = (col + 0.5f)*(1.f/128.f) - 1.f;
    float gy = (row + 0.5f)*(1.f/128.f) - 1.f;
    float px = ((gx + 1.f)*128.f - 1.f)*0.5f;
    float py = ((gy + 1.f)*128.f - 1.f)*0.5f;
    float x0f = floorf(px), y0f = floorf(py);
    int x0 = (int)x0f, y0 = (int)y0f;
    float wx1 = px - x0f, wy1 = py - y0f;
    int img = b*4 + n;
    const float* base = ext + ((size_t)img << 22) + ch;
    float acc = 0.f;
    float w00 = (1.f-wy1)*(1.f-wx1);
    if (y0 >= 0 && y0 <= 127 && x0 >= 0 && x0 <= 127)         acc += base[(size_t)((y0<<7)+x0) << 8]*w00;
    float w01 = (1.f-wy1)*wx1;
    if (y0 >= 0 && y0 <= 127 && x0+1 >= 0 && x0+1 <= 127)     acc += base[(size_t)((y0<<7)+x0+1) << 8]*w01;
    float w10 = wy1*(1.f-wx1);
    if (y0+1 >= 0 && y0+1 <= 127 && x0 >= 0 && x0 <= 127)     acc += base[(size_t)(((y0+1)<<7)+x0) << 8]*w10;
    float w11 = wy1*wx1;
    if (y0+1 >= 0 && y0+1 <= 127 && x0+1 >= 0 && x0+1 <= 127) acc += base[(size_t)(((y0+1)<<7)+x0+1) << 8]*w11;
    out = acc;
  } else {
    int c = ch - 255;
    float iv = ldin(polar, (((size_t)(b*4+n)*4 + c)<<16) + id, f32);
    float mv = ldin(mask, (b<<16) + id, f32);
    out = iv*mv;
  }
  short hh, ll; splitbf(out, hh, ll);
  cath[t] = hh; catl[t] = ll;
}

// ---------------- weight transpose+split: Wt[N][Kp] ----------------
__global__ __launch_bounds__(256) void wt_k(const void* __restrict__ src,
    short* __restrict__ dhi, short* __restrict__ dlo,
    int K, int N, int Kp, const int* __restrict__ flagp)
{
  int f32 = *flagp;
  int t = blockIdx.x*256 + threadIdx.x;
  if (t >= N*Kp) return;
  int n = t / Kp, k = t % Kp;
  short hi = 0, lo = 0;
  if (k < K) splitbf(ldin(src, (size_t)k*N + n, f32), hi, lo);
  dhi[t] = hi; dlo[t] = lo;
}

// ---------------- bf16x3 MFMA GEMM, 128x128 tile, async gload_lds staging ----------------
// REQUIRES K % 32 == 0 and Kp == K (callers: conv K=64, ia_qkv K=256, ia_ff1 K=256)
__global__ __launch_bounds__(256) void gemm_mfma_k(
    const short* __restrict__ Ah_g, const short* __restrict__ Al_g, int As,
    const short* __restrict__ Bh, const short* __restrict__ Bl, int Kp,
    short* __restrict__ Ch, short* __restrict__ Cl, float* __restrict__ Cf,
    int M, int K, int N, int relu,
    const void* __restrict__ bias, int biasN, const int* __restrict__ flagp)
{
  __shared__ __align__(16) short AhL[128*32];
  __shared__ __align__(16) short AlL[128*32];
  __shared__ __align__(16) short BhL[128*32];
  __shared__ __align__(16) short BlL[128*32];
  int tid = threadIdx.x;
  int lane = tid & 63, wid = tid >> 6;
  int wr = wid >> 1, wc = wid & 1;
  int l15 = lane & 15, lg = lane >> 4;
  int brow = blockIdx.y*128, bcol = blockIdx.x*128;
  int r0 = tid >> 2, cs = (tid & 3)*8;   // staging: row-within-pass, 16B chunk
  f4v acc[4][4] = {};

  for (int k0 = 0; k0 < K; k0 += 32) {
    __syncthreads();   // previous iteration's ds_reads complete before overwrite
    #pragma unroll
    for (int i = 0; i < 2; ++i) {
      int row = i*64 + r0;
      size_t aoff = (size_t)(brow + row)*As + k0 + cs;
      size_t boff = (size_t)(bcol + row)*Kp + k0 + cs;
      int loff = row*32 + cs;           // == (i*2048 + tid*8): tid-linear, 16B/lane
      gl16(Ah_g + aoff, &AhL[loff]);
      gl16(Al_g + aoff, &AlL[loff]);
      gl16(Bh  + boff, &BhL[loff]);
      gl16(Bl  + boff, &BlL[loff]);
    }
    __syncthreads();   // compiler drains vmcnt before barrier -> LDS ready

    s8v ah[4], al[4], bh[4], bl[4];
    #pragma unroll
    for (int m = 0; m < 4; ++m) {
      ah[m] = *(const s8v*)&AhL[(wr*64 + m*16 + l15)*32 + lg*8];
      al[m] = *(const s8v*)&AlL[(wr*64 + m*16 + l15)*32 + lg*8];
    }
    #pragma unroll
    for (int n = 0; n < 4; ++n) {
      bh[n] = *(const s8v*)&BhL[(wc*64 + n*16 + l15)*32 + lg*8];
      bl[n] = *(const s8v*)&BlL[(wc*64 + n*16 + l15)*32 + lg*8];
    }
    #pragma unroll
    for (int m = 0; m < 4; ++m)
      #pragma unroll
      for (int n = 0; n < 4; ++n) {
        f4v t = acc[m][n];
        t = __builtin_amdgcn_mfma_f32_16x16x32_bf16(ah[m], bh[n], t, 0, 0, 0);
        t = __builtin_amdgcn_mfma_f32_16x16x32_bf16(al[m], bh[n], t, 0, 0, 0);
        t = __builtin_amdgcn_mfma_f32_16x16x32_bf16(ah[m], bl[n], t, 0, 0, 0);
        acc[m][n] = t;
      }
  }

  int f32 = bias ? *flagp : 0;
  #pragma unroll
  for (int m = 0; m < 4; ++m)
    #pragma unroll
    for (int n = 0; n < 4; ++n)
      #pragma unroll
      for (int r = 0; r < 4; ++r) {
        int row = brow + wr*64 + m*16 + lg*4 + r;
        int col = bcol + wc*64 + n*16 + l15;
        float v = acc[m][n][r];
        if (bias && col < biasN) v += ldin(bias, col, f32);
        if (relu) v = fmaxf(v, 0.f);
        size_t idx = (size_t)row*N + col;
        if (Cf) Cf[idx] = v;
        else { short hh, ll; splitbf(v, hh, ll); Ch[idx] = hh; Cl[idx] = ll; }
      }
}

// ---------------- bf16x3 MFMA GEMM, 64x64 tile (reg-staged; handles K%32!=0 via Kp pad) ----------------
__global__ __launch_bounds__(256) void gemm_mfma64_k(
    const short* __restrict__ Ah_g, const short* __restrict__ Al_g, int As,
    const short* __restrict__ Bh, const short* __restrict__ Bl, int Kp,
    short* __restrict__ Ch, short* __restrict__ Cl,
    int M, int K, int N, int relu)
{
  __shared__ __align__(16) short AhL[64*40];
  __shared__ __align__(16) short AlL[64*40];
  __shared__ __align__(16) short BhL[64*40];
  __shared__ __align__(16) short BlL[64*40];
  int tid = threadIdx.x;
  int lane = tid & 63, wid = tid >> 6;
  int wr = wid >> 1, wc = wid & 1;
  int l15 = lane & 15, lg = lane >> 4;
  int brow = blockIdx.y*64, bcol = blockIdx.x*64;
  int srow = tid >> 2, skc = (tid & 3)*8;
  const short* asegh = Ah_g + (size_t)(brow + srow)*As;
  const short* asegl = Al_g + (size_t)(brow + srow)*As;
  const short* bsegh = Bh + (size_t)(bcol + srow)*Kp;
  const short* bsegl = Bl + (size_t)(bcol + srow)*Kp;
  f4v acc[2][2] = {};

  for (int k0 = 0; k0 < K; k0 += 32) {
    __syncthreads();
    int gk = k0 + skc;
    *(s8v*)&AhL[srow*40 + skc] = *(const s8v*)(asegh + gk);
    *(s8v*)&AlL[srow*40 + skc] = *(const s8v*)(asegl + gk);
    {
      s8v h0 = 0, l0 = 0;
      if (gk < Kp) { h0 = *(const s8v*)(bsegh + gk); l0 = *(const s8v*)(bsegl + gk); }
      *(s8v*)&BhL[srow*40 + skc] = h0;
      *(s8v*)&BlL[srow*40 + skc] = l0;
    }
    __syncthreads();
    s8v ah[2], al[2], bh[2], bl[2];
    #pragma unroll
    for (int m = 0; m < 2; ++m) {
      ah[m] = *(const s8v*)&AhL[(wr*32 + m*16 + l15)*40 + lg*8];
      al[m] = *(const s8v*)&AlL[(wr*32 + m*16 + l15)*40 + lg*8];
    }
    #pragma unroll
    for (int n = 0; n < 2; ++n) {
      bh[n] = *(const s8v*)&BhL[(wc*32 + n*16 + l15)*40 + lg*8];
      bl[n] = *(const s8v*)&BlL[(wc*32 + n*16 + l15)*40 + lg*8];
    }
    #pragma unroll
    for (int m = 0; m < 2; ++m)
      #pragma unroll
      for (int n = 0; n < 2; ++n) {
        f4v t = acc[m][n];
        t = __builtin_amdgcn_mfma_f32_16x16x32_bf16(ah[m], bh[n], t, 0, 0, 0);
        t = __builtin_amdgcn_mfma_f32_16x16x32_bf16(al[m], bh[n], t, 0, 0, 0);
        t = __builtin_amdgcn_mfma_f32_16x16x32_bf16(ah[m], bl[n], t, 0, 0, 0);
        acc[m][n] = t;
      }
  }

  #pragma unroll
  for (int m = 0; m < 2; ++m)
    #pragma unroll
    for (int n = 0; n < 2; ++n)
      #pragma unroll
      for (int r = 0; r < 4; ++r) {
        int row = brow + wr*32 + m*16 + lg*4 + r;
        int col = bcol + wc*32 + n*16 + l15;
        float v = acc[m][n][r];
        if (relu) v = fmaxf(v, 0.f);
        size_t idx = (size_t)row*N + col;
        short hh, ll; splitbf(v, hh, ll);
        Ch[idx] = hh; Cl[idx] = ll;
      }
}

// ---------------- LayerNorm on split planes ----------------
__global__ __launch_bounds__(256) void ln_k(const short* __restrict__ xh,
    const short* __restrict__ xl, const short* __restrict__ rh, const short* __restrict__ rl,
    const void* __restrict__ g, const void* __restrict__ bta,
    short* __restrict__ oh, short* __restrict__ ol, int D, const int* __restrict__ flagp)
{
  int f32 = *flagp;
  int row = blockIdx.x;
  size_t base = (size_t)row*D;
  float s = 0.f, s2 = 0.f;
  for (int i = threadIdx.x; i < D; i += 256) {
    float v = bs2f(xh[base+i]) + bs2f(xl[base+i]) + bs2f(rh[base+i]) + bs2f(rl[base+i]);
    s += v; s2 += v*v;
  }
  #pragma unroll
  for (int o = 32; o; o >>= 1) { s += __shfl_down(s, o); s2 += __shfl_down(s2, o); }
  __shared__ float as_[4], as2[4];
  __shared__ float mean_s, inv_s;
  int wv = threadIdx.x >> 6;
  if ((threadIdx.x & 63) == 0) { as_[wv] = s; as2[wv] = s2; }
  __syncthreads();
  if (threadIdx.x == 0) {
    float S = as_[0]+as_[1]+as_[2]+as_[3];
    float S2 = as2[0]+as2[1]+as2[2]+as2[3];
    float m = S / (float)D;
    float var = S2/(float)D - m*m;
    mean_s = m; inv_s = rsqrtf(var + 1e-5f);
  }
  __syncthreads();
  float m = mean_s, inv = inv_s;
  for (int i = threadIdx.x; i < D; i += 256) {
    float v = bs2f(xh[base+i]) + bs2f(xl[base+i]) + bs2f(rh[base+i]) + bs2f(rl[base+i]);
    float res = (v - m)*inv*ldin(g, i, f32) + ldin(bta, i, f32);
    short hh, ll; splitbf(res, hh, ll);
    oh[base+i] = hh; ol[base+i] = ll;
  }
}

// ---------------- ia attention (T=4) on split planes ----------------
__global__ __launch_bounds__(256) void attn_small_k(const short* __restrict__ qh,
    const short* __restrict__ ql, short* __restrict__ oh, short* __restrict__ ol)
{
  int t = blockIdx.x*256 + threadIdx.x;
  if (t >= BP_*8*4) return;
  int qn = t & 3, h = (t >> 2) & 7, bp = t >> 5;
  size_t base = (size_t)bp*4*768;
  size_t qoff = base + qn*768 + h*32;
  float qv[32];
  #pragma unroll
  for (int i = 0; i < 32; ++i) qv[i] = bs2f(qh[qoff+i]) + bs2f(ql[qoff+i]);
  float s[4]; float mx = -1e30f;
  #pragma unroll
  for (int kn = 0; kn < 4; ++kn) {
    size_t koff = base + kn*768 + 256 + h*32;
    float d = 0.f;
    #pragma unroll
    for (int i = 0; i < 32; ++i) d += qv[i]*(bs2f(qh[koff+i]) + bs2f(ql[koff+i]));
    s[kn] = d * 0.17677669529663687f;
    mx = fmaxf(mx, s[kn]);
  }
  float sum = 0.f;
  #pragma unroll
  for (int kn = 0; kn < 4; ++kn) { s[kn] = expf(s[kn]-mx); sum += s[kn]; }
  float inv = 1.f/sum;
  size_t obase = (size_t)(bp*4 + qn)*256 + h*32;
  #pragma unroll
  for (int i = 0; i < 32; ++i) {
    float acc = 0.f;
    #pragma unroll
    for (int kn = 0; kn < 4; ++kn) {
      size_t voff = base + kn*768 + 512 + h*32 + i;
      acc += s[kn]*(bs2f(qh[voff]) + bs2f(ql[voff]));
    }
    short hh, ll; splitbf(acc*inv, hh, ll);
    oh[obase+i] = hh; ol[obase+i] = ll;
  }
}

__global__ __launch_bounds__(256) void enh_pos_k(const short* __restrict__ ph,
    const short* __restrict__ pl_, const int* __restrict__ ids,
    const void* __restrict__ pa_pos, short* __restrict__ zh, short* __restrict__ zl,
    const int* __restrict__ flagp)
{
  int f32 = *flagp;
  int t = blockIdx.x*256 + threadIdx.x;
  if (t >= BP_*384) return;
  int f = t % 384, bp = t / 384;
  size_t pb = (size_t)bp*4*384 + f;
  float v0 = bs2f(ph[pb])       + bs2f(pl_[pb]);
  float v1 = bs2f(ph[pb+384])   + bs2f(pl_[pb+384]);
  float v2 = bs2f(ph[pb+768])   + bs2f(pl_[pb+768]);
  float v3 = bs2f(ph[pb+1152])  + bs2f(pl_[pb+1152]);
  float m = fmaxf(fmaxf(v0, v1), fmaxf(v2, v3));
  int id = ids[bp];
  int row = id >> 8, col = id & 255;
  float gx = (col + 0.5f)*(1.f/128.f) - 1.f;
  float gy = (row + 0.5f)*(1.f/128.f) - 1.f;
  float res = m + gx*ldin(pa_pos, f, f32) + gy*ldin(pa_pos, 384 + f, f32);
  short hh, ll; splitbf(res, hh, ll);
  zh[t] = hh; zl[t] = ll;
}

// ---------------- global V transpose: qkvp planes -> VT[b][h][48][2048] hi/lo ----------------
__global__ __launch_bounds__(256) void vtr_k(const short* __restrict__ qh,
    const short* __restrict__ ql, short* __restrict__ vth, short* __restrict__ vtl)
{
  __shared__ short Th[128*58], Tl[128*58];
  int bid = blockIdx.x;
  int kt = bid & 15;        // kv tile of 128
  int h  = (bid >> 4) & 7;
  int b  = bid >> 7;
  int tid = threadIdx.x;
  int kv0 = kt*128;
  {
    int kv = tid >> 1, hf = tid & 1;
    const short* sh = qh + ((size_t)(b*2048 + kv0 + kv))*1152 + 768 + h*48 + hf*24;
    const short* sl = ql + ((size_t)(b*2048 + kv0 + kv))*1152 + 768 + h*48 + hf*24;
    short vh[24], vl[24];
    #pragma unroll
    for (int j = 0; j < 24; j += 8) {
      *(s8v*)&vh[j] = *(const s8v*)(sh + j);
      *(s8v*)&vl[j] = *(const s8v*)(sl + j);
    }
    #pragma unroll
    for (int j = 0; j < 24; ++j) {
      Th[kv*58 + hf*24 + j] = vh[j];
      Tl[kv*58 + hf*24 + j] = vl[j];
    }
  }
  __syncthreads();
  for (int idx = tid; idx < 384; idx += 256) {
    int d = idx >> 3, ch = idx & 7;      // ch: chunk of 16 kv
    short oh[16], olv[16];
    #pragma unroll
    for (int j = 0; j < 16; ++j) {
      int kv = ch*16 + j;
      oh[j]  = Th[kv*58 + d];
      olv[j] = Tl[kv*58 + d];
    }
    size_t dst = ((size_t)((b*8 + h)*48 + d))*2048 + kv0 + ch*16;
    *(s8v*)(vth + dst)     = *(s8v*)&oh[0];
    *(s8v*)(vth + dst + 8) = *(s8v*)&oh[8];
    *(s8v*)(vtl + dst)     = *(s8v*)&olv[0];
    *(s8v*)(vtl + dst + 8) = *(s8v*)&olv[8];
  }
}

// ---------------- pa attention v4: flash bf16x3, KVBLK=64, LDS-staged, global VT ----------------
__global__ __launch_bounds__(256) void attn_big4_k(const short* __restrict__ qh,
    const short* __restrict__ ql, const short* __restrict__ vth, const short* __restrict__ vtl,
    float* __restrict__ po, float* __restrict__ pm, float* __restrict__ pl)
{
  __shared__ __align__(16) short KSh[64*72], KSl[64*72];
  __shared__ __align__(16) short VTh[48*72], VTl[48*72];
  __shared__ __align__(16) short PSh[4][16*72], PSl[4][16*72];
  int bid = blockIdx.x;
  int sp = bid % SPLITS;
  int rem = bid / SPLITS;
  int qt = rem & 31;
  int h  = (rem >> 5) & 7;
  int b  = rem >> 8;
  int tid = threadIdx.x, lane = tid & 63, w = tid >> 6;
  int l15 = lane & 15, lg = lane >> 4;

  s8v qfh[2], qfl[2];
  {
    int q = qt*64 + w*16 + l15;
    const short* bh = qh + ((size_t)(b*2048 + q))*1152 + h*48;
    const short* bl = ql + ((size_t)(b*2048 + q))*1152 + h*48;
    #pragma unroll
    for (int ks = 0; ks < 2; ++ks) {
      int d0 = ks*32 + lg*8;
      if (d0 < 48) { qfh[ks] = *(const s8v*)(bh + d0); qfl[ks] = *(const s8v*)(bl + d0); }
      else         { qfh[ks] = 0; qfl[ks] = 0; }
    }
  }
  // zero K pad region d=48..63 once (64 kv rows x 16 d x 2 planes)
  for (int idx = tid; idx < 2048; idx += 256) {
    int hl = idx >> 10, j = idx & 1023;
    int kv = j >> 4, dd = 48 + (j & 15);
    short* dst = hl ? KSl : KSh;
    dst[kv*72 + dd] = 0;
  }

  f4v oacc[3] = {};
  float mrun[4] = {-1e30f, -1e30f, -1e30f, -1e30f};
  float lrun[4] = {0.f, 0.f, 0.f, 0.f};
  const float scale = 0.14433756729740643f;
  int kvbase = sp*(2048/SPLITS);
  const short* vthb = vth + ((size_t)(b*8 + h)*48)*2048;
  const short* vtlb = vtl + ((size_t)(b*8 + h)*48)*2048;

  for (int kt = 0; kt < 2048/SPLITS/64; ++kt) {
    __syncthreads();
    int kv0 = kvbase + kt*64;
    // stage K tile: 64 rows x 48 d, hi+lo (vector copies)
    for (int idx = tid; idx < 768; idx += 256) {
      int hl = idx >= 384; int j = hl ? idx - 384 : idx;
      int kv = j / 6, seg = j % 6;
      const short* src = (hl ? ql : qh) + ((size_t)(b*2048 + kv0 + kv))*1152 + 384 + h*48 + seg*8;
      short* dst = hl ? KSl : KSh;
      *(s8v*)&dst[kv*72 + seg*8] = *(const s8v*)src;
    }
    // stage V^T tile: 48 d x 64 kv, hi+lo from global VT (vector copies)
    for (int idx = tid; idx < 384; idx += 256) {
      int hl = idx >= 192; int j = hl ? idx - 192 : idx;
      int d = j >> 2, sg = j & 3;
      const short* src = (hl ? vtlb : vthb) + (size_t)d*2048 + kv0 + sg*16;
      short* dst = hl ? VTl : VTh;
      *(s8v*)&dst[d*72 + sg*16]     = *(const s8v*)src;
      *(s8v*)&dst[d*72 + sg*16 + 8] = *(const s8v*)(src + 8);
    }
    __syncthreads();

    // S = Q K^T over 64 kv (4 col-blocks)
    f4v s[4];
    #pragma unroll
    for (int nb = 0; nb < 4; ++nb) {
      f4v t = {};
      #pragma unroll
      for (int ks = 0; ks < 2; ++ks) {
        s8v kh = *(const s8v*)&KSh[(nb*16 + l15)*72 + ks*32 + lg*8];
        s8v kl = *(const s8v*)&KSl[(nb*16 + l15)*72 + ks*32 + lg*8];
        t = __builtin_amdgcn_mfma_f32_16x16x32_bf16(qfh[ks], kh, t, 0, 0, 0);
        t = __builtin_amdgcn_mfma_f32_16x16x32_bf16(qfl[ks], kh, t, 0, 0, 0);
        t = __builtin_amdgcn_mfma_f32_16x16x32_bf16(qfh[ks], kl, t, 0, 0, 0);
      }
      s[nb] = t * scale;
    }
    // online softmax: lane holds rows lg*4+r, cols nb*16+l15
    float mnew[4], alpha[4], rsum[4];
    #pragma unroll
    for (int r = 0; r < 4; ++r) {
      float pmx = fmaxf(fmaxf(s[0][r], s[1][r]), fmaxf(s[2][r], s[3][r]));
      #pragma unroll
      for (int off = 1; off < 16; off <<= 1) pmx = fmaxf(pmx, __shfl_xor(pmx, off));
      mnew[r] = fmaxf(mrun[r], pmx);
      alpha[r] = __expf(mrun[r] - mnew[r]);
      rsum[r] = 0.f;
    }
    #pragma unroll
    for (int nb = 0; nb < 4; ++nb)
      #pragma unroll
      for (int r = 0; r < 4; ++r) {
        float p = __expf(s[nb][r] - mnew[r]);
        s[nb][r] = p;
        rsum[r] += p;
      }
    #pragma unroll
    for (int r = 0; r < 4; ++r) {
      float rs = rsum[r];
      #pragma unroll
      for (int off = 1; off < 16; off <<= 1) rs += __shfl_xor(rs, off);
      lrun[r] = lrun[r]*alpha[r] + rs;
      mrun[r] = mnew[r];
    }
    // P split -> per-wave LDS [16 q][64 kv], stride 72
    #pragma unroll
    for (int nb = 0; nb < 4; ++nb)
      #pragma unroll
      for (int r = 0; r < 4; ++r) {
        short hh, ll; splitbf(s[nb][r], hh, ll);
        PSh[w][(lg*4 + r)*72 + nb*16 + l15] = hh;
        PSl[w][(lg*4 + r)*72 + nb*16 + l15] = ll;
      }
    // rescale O
    #pragma unroll
    for (int db = 0; db < 3; ++db)
      #pragma unroll
      for (int r = 0; r < 4; ++r)
        oacc[db][r] *= alpha[r];
    // O += P V over kv=64 (two 32-slots)
    s8v pf_h[2], pf_l[2];
    #pragma unroll
    for (int ks = 0; ks < 2; ++ks) {
      pf_h[ks] = *(const s8v*)&PSh[w][l15*72 + ks*32 + lg*8];
      pf_l[ks] = *(const s8v*)&PSl[w][l15*72 + ks*32 + lg*8];
    }
    #pragma unroll
    for (int db = 0; db < 3; ++db) {
      f4v t = oacc[db];
      #pragma unroll
      for (int ks = 0; ks < 2; ++ks) {
        s8v vh = *(const s8v*)&VTh[(db*16 + l15)*72 + ks*32 + lg*8];
        s8v vl = *(const s8v*)&VTl[(db*16 + l15)*72 + ks*32 + lg*8];
        t = __builtin_amdgcn_mfma_f32_16x16x32_bf16(pf_h[ks], vh, t, 0, 0, 0);
        t = __builtin_amdgcn_mfma_f32_16x16x32_bf16(pf_l[ks], vh, t, 0, 0, 0);
        t = __builtin_amdgcn_mfma_f32_16x16x32_bf16(pf_h[ks], vl, t, 0, 0, 0);
      }
      oacc[db] = t;
    }
  }

  #pragma unroll
  for (int db = 0; db < 3; ++db)
    #pragma unroll
    for (int r = 0; r < 4; ++r) {
      int q = qt*64 + w*16 + lg*4 + r;
      po[((size_t)(sp*BP_ + b*2048 + q))*384 + h*48 + db*16 + l15] = oacc[db][r];
    }
  if (l15 == 0) {
    #pragma unroll
    for (int r = 0; r < 4; ++r) {
      int q = qt*64 + w*16 + lg*4 + r;
      pm[((size_t)(sp*BP_ + b*2048 + q))*8 + h] = mrun[r];
      pl[((size_t)(sp*BP_ + b*2048 + q))*8 + h] = lrun[r];
    }
  }
}

// merge SPLITS partials (exact logsumexp combine)
__global__ __launch_bounds__(256) void attn_merge_k(const float* __restrict__ po,
    const float* __restrict__ pm, const float* __restrict__ pl,
    short* __restrict__ oh, short* __restrict__ ol)
{
  int t = blockIdx.x*256 + threadIdx.x;
  if (t >= BP_*384) return;
  int bp = t / 384, f = t - bp*384;
  int h = f / 48;
  float M = -1e30f;
  #pragma unroll
  for (int sp = 0; sp < SPLITS; ++sp)
    M = fmaxf(M, pm[((size_t)(sp*BP_ + bp))*8 + h]);
  float num = 0.f, den = 0.f;
  #pragma unroll
  for (int sp = 0; sp < SPLITS; ++sp) {
    float wgt = __expf(pm[((size_t)(sp*BP_ + bp))*8 + h] - M);
    num += po[((size_t)(sp*BP_ + bp))*384 + f]*wgt;
    den += pl[((size_t)(sp*BP_ + bp))*8 + h]*wgt;
  }
  float res = num/den;
  short hh, ll; splitbf(res, hh, ll);
  oh[t] = hh; ol[t] = ll;
}

// ---------------- heads: one wave per bp row, coalesced + shuffle reduce ----------------
__global__ __launch_bounds__(256) void heads_k(const short* __restrict__ gh,
    const short* __restrict__ gl, const void* __restrict__ hn, const void* __restrict__ hp,
    float* __restrict__ raw5, const int* __restrict__ flagp)
{
  int f32 = *flagp;
  int gtid = blockIdx.x*256 + threadIdx.x;
  int bp = gtid >> 6;
  if (bp >= BP_) return;
  int lane = gtid & 63;
  size_t base = (size_t)bp*384;
  float n0=0,n1=0,n2=0,p0=0,p1=0;
  #pragma unroll
  for (int it = 0; it < 6; ++it) {
    int k = lane + it*64;
    float gv = bs2f(gh[base+k]) + bs2f(gl[base+k]);
    n0 += gv*ldin(hn, k*3+0, f32);
    n1 += gv*ldin(hn, k*3+1, f32);
    n2 += gv*ldin(hn, k*3+2, f32);
    p0 += gv*ldin(hp, k*2+0, f32);
    p1 += gv*ldin(hp, k*2+1, f32);
  }
  #pragma unroll
  for (int off = 32; off; off >>= 1) {
    n0 += __shfl_down(n0, off);
    n1 += __shfl_down(n1, off);
    n2 += __shfl_down(n2, off);
    p0 += __shfl_down(p0, off);
    p1 += __shfl_down(p1, off);
  }
  if (lane == 0) {
    raw5[bp*5+0]=n0; raw5[bp*5+1]=n1; raw5[bp*5+2]=n2;
    raw5[bp*5+3]=p0; raw5[bp*5+4]=p1;
  }
}

__global__ __launch_bounds__(256) void zero_out_k(void* __restrict__ out, int n,
    const int* __restrict__ flagp)
{
  int f32 = *flagp;
  int t = blockIdx.x*256 + threadIdx.x;
  if (t < n) stout(out, t, 0.f, f32);
}

__global__ __launch_bounds__(256) void wm_init_k(int* __restrict__ wm)
{
  int t = blockIdx.x*256 + threadIdx.x;
  if (t < 2*65536) wm[t] = -1;
}

__global__ __launch_bounds__(256) void wm_mark_k(const int* __restrict__ ids, int* __restrict__ wm)
{
  int t = blockIdx.x*256 + threadIdx.x;
  if (t >= BP_) return;
  int b = t >> 11, p = t & 2047;
  atomicMax(&wm[(b<<16) + ids[t]], p);
}

__global__ __launch_bounds__(256) void scatter_k(const int* __restrict__ ids,
    const int* __restrict__ wm, const float* __restrict__ raw5, void* __restrict__ out,
    const int* __restrict__ flagp)
{
  int f32 = *flagp;
  int t = blockIdx.x*256 + threadIdx.x;
  if (t >= BP_) return;
  int b = t >> 11, p = t & 2047;
  int id = ids[t];
  if (wm[(b<<16) + id] != p) return;
  float n0 = raw5[t*5+0], n1 = raw5[t*5+1], n2 = raw5[t*5+2];
  float inv = 1.f / fmaxf(sqrtf(n0*n0 + n1*n1 + n2*n2), 1e-12f);
  stout(out, ((size_t)(b*3+0)<<16) + id, n0*inv, f32);
  stout(out, ((size_t)(b*3+1)<<16) + id, n1*inv, f32);
  stout(out, ((size_t)(b*3+2)<<16) + id, n2*inv, f32);
  size_t matoff = (size_t)B_*3*65536;
  stout(out, matoff + ((size_t)(b*2+0)<<16) + id, raw5[t*5+3], f32);
  stout(out, matoff + ((size_t)(b*2+1)<<16) + id, raw5[t*5+4], f32);
}

// ---------------- host ----------------
extern "C" void kernel_launch(void* const* d_in, const int* in_sizes, int n_in,
                              void* d_out, int out_size, void* d_ws, size_t ws_size,
                              hipStream_t stream)
{
  const void* polar   = d_in[0];
  const void* mask    = d_in[1];
  const void* pprop   = d_in[2];
  const void* conv_w  = d_in[3];
  const void* conv_b  = d_in[4];
  const void* ia_win  = d_in[5];
  const void* ia_qkv  = d_in[6];
  const void* ia_out  = d_in[7];
  const void* ia_ln1g = d_in[8];
  const void* ia_ln1b = d_in[9];
  const void* ia_ff1  = d_in[10];
  const void* ia_ff2  = d_in[11];
  const void* ia_ln2g = d_in[12];
  const void* ia_ln2b = d_in[13];
  const void* ia_proj = d_in[14];
  const void* pa_pos  = d_in[15];
  const void* pa_qkv  = d_in[16];
  const void* pa_out  = d_in[17];
  const void* pa_ln1g = d_in[18];
  const void* pa_ln1b = d_in[19];
  const void* pa_ff1  = d_in[20];
  const void* pa_ff2  = d_in[21];
  const void* pa_ln2g = d_in[22];
  const void* pa_ln2b = d_in[23];
  const void* head_n  = d_in[24];
  const void* head_p  = d_in[25];
  const int*  ids     = (const int*)d_in[26];

  float* ws = nullptr;
  hipGetSymbolAddress((void**)&ws, HIP_SYMBOL(g_scratch));

  float* xbuf   = ws + OFF_X;
  float* extA   = ws + OFF_EXTA;
  float* extB   = ws + OFF_EXTB;
  short* path    = (short*)(ws + OFF_EXTB);  short* patl    = path    + PS_PAT;
  short* cath    = (short*)(ws + OFF_CAT);   short* catl    = cath    + PS_CAT;
  short* tokh    = (short*)(ws + OFF_TOK);   short* tokl    = tokh    + PS_256;
  short* qkvh    = (short*)(ws + OFF_QKV);   short* qkvl    = qkvh    + PS_QKV;
  short* attnoh  = (short*)(ws + OFF_ATTNO); short* attnol  = attnoh  + PS_256;
  short* tmp256h = (short*)(ws + OFF_TMP256);short* tmp256l = tmp256h + PS_256;
  short* y1h     = (short*)(ws + OFF_Y1);    short* y1l     = y1h     + PS_256;
  short* ffh     = (short*)(ws + OFF_FF);    short* ffl     = ffh     + PS_FF;
  short* tmp256bh= (short*)(ws + OFF_TMP256B);short* tmp256bl= tmp256bh + PS_256;
  short* y2h     = (short*)(ws + OFF_Y2);    short* y2l     = y2h     + PS_256;
  short* projh   = (short*)(ws + OFF_PROJ);  short* projl   = projh   + PS_PROJ;
  short* zh      = (short*)(ws + OFF_Z);     short* zl      = zh      + PS_384;
  short* qkvph   = (short*)(ws + OFF_QKVP);  short* qkvpl   = qkvph   + PS_QKVP;
  short* attnph  = (short*)(ws + OFF_ATTNP); short* attnpl  = attnph  + PS_384;
  short* tmp384h = (short*)(ws + OFF_TMP384);short* tmp384l = tmp384h + PS_384;
  short* z2h     = (short*)(ws + OFF_Z2);    short* z2l     = z2h     + PS_384;
  short* ffb2h   = (short*)(ws + OFF_FFB2);  short* ffb2l   = ffb2h   + PS_FF2;
  short* tmp384bh= (short*)(ws + OFF_TMP384B);short* tmp384bl= tmp384bh + PS_384;
  short* glbh    = (short*)(ws + OFF_GLB);   short* glbl    = glbh    + PS_384;
  float* raw5   = ws + OFF_RAW5;
  int*   wm     = (int*)(ws + OFF_WM);
  int*   flagp  = (int*)(ws + OFF_FLAG);
  short* wtb    = (short*)(ws + OFF_WTB);
  short* wtb_lo = wtb + WT_LO_OFF;
  float* pobuf  = ws + OFF_PO;
  float* pmbuf  = ws + OFF_PM;
  float* plbuf  = ws + OFF_PL;
  short* vth    = (short*)(ws + OFF_VT);
  short* vtl    = vth + PS_VT;

  probe_k<<<1, 64, 0, stream>>>((const unsigned int*)mask, flagp);

  struct WDesc { const void* src; int K, N, Kp; size_t off; };
  size_t woff = 0;
  auto pad16 = [](int k){ return (k + 15) & ~15; };
  WDesc wd[10];
  const void* srcs[10] = {ia_win, ia_qkv, ia_out, ia_ff1, ia_ff2, ia_proj, pa_qkv, pa_out, pa_ff1, pa_ff2};
  int Ks[10]   = {259, 256, 256, 256, 1024, 256, 384, 384, 384, 1024};
  int Ns[10]   = {256, 768, 256, 1024, 256, 384, 1152, 384, 1024, 384};
  for (int i = 0; i < 10; ++i) {
    wd[i] = {srcs[i], Ks[i], Ns[i], pad16(Ks[i]), woff};
    woff += (size_t)wd[i].N * wd[i].Kp;
    int tot = wd[i].N * wd[i].Kp;
    wt_k<<<(tot + 255)/256, 256, 0, stream>>>(wd[i].src, wtb + wd[i].off, wtb_lo + wd[i].off,
                                              wd[i].K, wd[i].N, wd[i].Kp, flagp);
  }
  wt_conv_k<<<(256*64)/256, 256, 0, stream>>>(conv_w, wtb + WT_CONV_HI, wtb + WT_CONV_LO, flagp);

  int use64[10] = {1, 0, 1, 0, 1, 1, 1, 1, 1, 1};
  auto gemm = [&](const short* Ahp, const short* Alp, int As, int wi,
                  short* Chp, short* Clp, int M, int relu) {
    if (use64[wi]) {
      dim3 bl(256), gr(wd[wi].N/64, M/64);
      gemm_mfma64_k<<<gr, bl, 0, stream>>>(Ahp, Alp, As, wtb + wd[wi].off, wtb_lo + wd[wi].off,
                                           wd[wi].Kp, Chp, Clp, M, wd[wi].K, wd[wi].N, relu);
    } else {
      dim3 bl(256), gr(wd[wi].N/128, M/128);
      gemm_mfma_k<<<gr, bl, 0, stream>>>(Ahp, Alp, As, wtb + wd[wi].off, wtb_lo + wd[wi].off,
                                         wd[wi].Kp, Chp, Clp, nullptr,
                                         M, wd[wi].K, wd[wi].N, relu, nullptr, 0, flagp);
    }
  };

  // stage 1: build, im2col(split), conv-as-GEMM (fp32 out, gload_lds staging), LDS gauss
  build_x_k<<<(int)((SZ_X+255)/256), 256, 0, stream>>>(polar, mask, pprop, flagp, xbuf);
  im2col_k<<<(int)((PS_PAT+255)/256), 256, 0, stream>>>(xbuf, path, patl);
  {
    dim3 bl(256), gr(256/128, CONV_M/128);
    gemm_mfma_k<<<gr, bl, 0, stream>>>(path, patl, 64, wtb + WT_CONV_HI, wtb + WT_CONV_LO, 64,
                                       nullptr, nullptr, extA,
                                       CONV_M, 64, 256, 1, conv_b, 255, flagp);
  }
  gauss2_k<1><<<8*128*4, 256, 0, stream>>>(extA, extB);
  gauss2_k<0><<<8*128*4, 256, 0, stream>>>(extB, extA);

  // stage 2
  sample_k<<<(int)((PS_CAT+255)/256), 256, 0, stream>>>(extA, polar, mask, ids, flagp, cath, catl);
  gemm(cath, catl, 288, 0, tokh, tokl, ROWS_IA, 0);

  // stage 3: ia transformer (T=4)
  gemm(tokh, tokl, 256, 1, qkvh, qkvl, ROWS_IA, 0);
  attn_small_k<<<(BP_*8*4)/256, 256, 0, stream>>>(qkvh, qkvl, attnoh, attnol);
  gemm(attnoh, attnol, 256, 2, tmp256h, tmp256l, ROWS_IA, 0);
  ln_k<<<ROWS_IA, 256, 0, stream>>>(tmp256h, tmp256l, tokh, tokl, ia_ln1g, ia_ln1b, y1h, y1l, 256, flagp);
  gemm(y1h, y1l, 256, 3, ffh, ffl, ROWS_IA, 1);
  gemm(ffh, ffl, 1024, 4, tmp256bh, tmp256bl, ROWS_IA, 0);
  ln_k<<<ROWS_IA, 256, 0, stream>>>(tmp256bh, tmp256bl, y1h, y1l, ia_ln2g, ia_ln2b, y2h, y2l, 256, flagp);

  // stage 4
  gemm(y2h, y2l, 256, 5, projh, projl, ROWS_IA, 0);
  enh_pos_k<<<(BP_*384)/256, 256, 0, stream>>>(projh, projl, ids, pa_pos, zh, zl, flagp);

  // stage 5: pa transformer (T=2048)
  gemm(zh, zl, 384, 6, qkvph, qkvpl, BP_, 0);
  vtr_k<<<B_*8*16, 256, 0, stream>>>(qkvph, qkvpl, vth, vtl);
  attn_big4_k<<<B_*8*32*SPLITS, 256, 0, stream>>>(qkvph, qkvpl, vth, vtl, pobuf, pmbuf, plbuf);
  attn_merge_k<<<(BP_*384)/256, 256, 0, stream>>>(pobuf, pmbuf, plbuf, attnph, attnpl);
  gemm(attnph, attnpl, 384, 7, tmp384h, tmp384l, BP_, 0);
  ln_k<<<BP_, 256, 0, stream>>>(tmp384h, tmp384l, zh, zl, pa_ln1g, pa_ln1b, z2h, z2l, 384, flagp);
  gemm(z2h, z2l, 384, 8, ffb2h, ffb2l, BP_, 1);
  gemm(ffb2h, ffb2l, 1024, 9, tmp384bh, tmp384bl, BP_, 0);
  ln_k<<<BP_, 256, 0, stream>>>(tmp384bh, tmp384bl, z2h, z2l, pa_ln2g, pa_ln2b, glbh, glbl, 384, flagp);

  // stage 6
  heads_k<<<(BP_*64 + 255)/256, 256, 0, stream>>>(glbh, glbl, head_n, head_p, raw5, flagp);
  zero_out_k<<<(out_size+255)/256, 256, 0, stream>>>(d_out, out_size, flagp);
  wm_init_k<<<(2*65536)/256, 256, 0, stream>>>(wm);
  wm_mark_k<<<(BP_+255)/256, 256, 0, stream>>>(ids, wm);
  scatter_k<<<(BP_+255)/256, 256, 0, stream>>>(ids, wm, raw5, d_out, flagp);
}

// Round 16
// 777.444 us; speedup vs baseline: 1.0173x; 1.0173x over previous
//
#include <hip/hip_runtime.h>
#include <hip/hip_bf16.h>
#include <math.h>

typedef __hip_bfloat16 bf16;
typedef __attribute__((ext_vector_type(8))) short s8v;   // 8 bf16 (4 VGPRs)
typedef __attribute__((ext_vector_type(4))) float f4v;   // MFMA acc

// ---------------- problem constants ----------------
#define B_   2
#define N_   4
#define H_   256
#define W_   256
#define P_   2048
#define CHF  255
#define BP_  (B_*P_)          // 4096
#define ROWS_IA (BP_*N_)      // 16384
#define NPIX 16384            // 128*128
#define CONV_M (8*NPIX)       // 131072
#define SPLITS 4              // attention KV split (KVBLK=64)

// ---------------- static scratch ----------------
constexpr size_t SZ_X      = (size_t)8*7*65536;
constexpr size_t SZ_EXT    = (size_t)8*NPIX*256;
constexpr size_t PS_CAT    = (size_t)ROWS_IA*288;
constexpr size_t PS_256    = (size_t)ROWS_IA*256;
constexpr size_t PS_QKV    = (size_t)ROWS_IA*768;
constexpr size_t PS_FF     = (size_t)ROWS_IA*1024;
constexpr size_t PS_PROJ   = (size_t)ROWS_IA*384;
constexpr size_t PS_384    = (size_t)BP_*384;
constexpr size_t PS_QKVP   = (size_t)BP_*1152;
constexpr size_t PS_FF2    = (size_t)BP_*1024;
constexpr size_t PS_PAT    = (size_t)CONV_M*64;
constexpr size_t SZ_WT     = 2347008;
constexpr size_t PS_VT     = (size_t)2*8*48*2048;   // shorts per VT plane

constexpr size_t OFF_X      = 0;
constexpr size_t OFF_EXTA   = OFF_X      + SZ_X;
constexpr size_t OFF_EXTB   = OFF_EXTA   + SZ_EXT;
constexpr size_t OFF_CAT    = OFF_EXTB   + SZ_EXT;
constexpr size_t OFF_TOK    = OFF_CAT    + PS_CAT;
constexpr size_t OFF_QKV    = OFF_TOK    + PS_256;
constexpr size_t OFF_ATTNO  = OFF_QKV    + PS_QKV;
constexpr size_t OFF_TMP256 = OFF_ATTNO  + PS_256;
constexpr size_t OFF_Y1     = OFF_TMP256 + PS_256;
constexpr size_t OFF_FF     = OFF_Y1     + PS_256;
constexpr size_t OFF_TMP256B= OFF_FF     + PS_FF;
constexpr size_t OFF_Y2     = OFF_TMP256B+ PS_256;
constexpr size_t OFF_PROJ   = OFF_Y2     + PS_256;
constexpr size_t OFF_Z      = OFF_PROJ   + PS_PROJ;
constexpr size_t OFF_QKVP   = OFF_Z      + PS_384;
constexpr size_t OFF_ATTNP  = OFF_QKVP   + PS_QKVP;
constexpr size_t OFF_TMP384 = OFF_ATTNP  + PS_384;
constexpr size_t OFF_Z2     = OFF_TMP384 + PS_384;
constexpr size_t OFF_FFB2   = OFF_Z2     + PS_384;
constexpr size_t OFF_TMP384B= OFF_FFB2   + PS_FF2;
constexpr size_t OFF_GLB    = OFF_TMP384B+ PS_384;
constexpr size_t OFF_RAW5   = OFF_GLB    + PS_384;
constexpr size_t OFF_WM     = OFF_RAW5   + (size_t)BP_*5;
constexpr size_t OFF_FLAG   = OFF_WM     + 2*65536;
constexpr size_t OFF_WTB    = OFF_FLAG   + 16;
constexpr size_t OFF_PO     = OFF_WTB    + SZ_WT;
constexpr size_t OFF_PM     = OFF_PO     + (size_t)SPLITS*BP_*384;
constexpr size_t OFF_PL     = OFF_PM     + (size_t)SPLITS*BP_*8;
constexpr size_t OFF_VT     = OFF_PL     + (size_t)SPLITS*BP_*8;
constexpr size_t N_FLOATS   = OFF_VT     + PS_VT;

__device__ __align__(256) float g_scratch[N_FLOATS];

constexpr size_t WT_LO_OFF   = 2330624;
constexpr size_t WT_CONV_HI  = 4661248;
constexpr size_t WT_CONV_LO  = WT_CONV_HI + 16384;

__constant__ float GW[11] = {
  0.398942278f, 0.241970724f, 0.0539909665f, 0.00443184841f,
  1.33830226e-4f, 1.48671951e-6f, 6.07588285e-9f, 9.13472041e-12f,
  5.05227108e-15f, 1.02797736e-18f, 7.69459863e-23f };

// ---------------- helpers ----------------
__device__ __forceinline__ float ldin(const void* p, size_t i, int f32) {
  return f32 ? ((const float*)p)[i] : __bfloat162float(((const bf16*)p)[i]);
}
__device__ __forceinline__ void stout(void* p, size_t i, float v, int f32) {
  if (f32) ((float*)p)[i] = v;
  else     ((bf16*)p)[i]  = __float2bfloat16(v);
}
__device__ __forceinline__ float bs2f(short s) {
  bf16 h = *reinterpret_cast<bf16*>(&s);
  return __bfloat162float(h);
}
__device__ __forceinline__ void splitbf(float f, short& hi, short& lo) {
  bf16 h = __float2bfloat16(f);
  float hf = __bfloat162float(h);
  bf16 l = __float2bfloat16(f - hf);
  hi = *reinterpret_cast<short*>(&h);
  lo = *reinterpret_cast<short*>(&l);
}

__global__ void probe_k(const unsigned int* __restrict__ m, int* __restrict__ flag)
{
  if (threadIdx.x == 0 && blockIdx.x == 0)
    *flag = (m[0] == 0x3F800000u) ? 1 : 0;
}

// ---------------- stage 1 ----------------
__global__ __launch_bounds__(256) void build_x_k(const void* __restrict__ polar,
    const void* __restrict__ mask, const void* __restrict__ pprop,
    const int* __restrict__ flagp, float* __restrict__ x)
{
  int f32 = *flagp;
  int t = blockIdx.x*256 + threadIdx.x;
  if (t >= (int)SZ_X) return;
  int pix = t & 65535;
  int c   = (t >> 16) % 7;
  int img = t / (7*65536);
  int b = img >> 2, n = img & 3;
  float mv = ldin(mask, (b<<16) + pix, f32);
  float v;
  if (c < 4)       v = ldin(polar, (((size_t)(b*4+n)*4 + c)<<16) + pix, f32) * mv;
  else if (c == 4) v = mv;
  else             v = ldin(pprop, (((size_t)(b*2 + (c-5)))<<16) + pix, f32) * mv;
  x[t] = v;
}

__global__ __launch_bounds__(256) void im2col_k(const float* __restrict__ x,
    short* __restrict__ ph, short* __restrict__ pl_)
{
  int t = blockIdx.x*256 + threadIdx.x;
  if (t >= (int)PS_PAT) return;
  int k = t & 63, row = t >> 6;
  int pix = row & (NPIX-1), img = row >> 14;
  int oy = pix >> 7, ox = pix & 127;
  float v = 0.f;
  if (k < 63) {
    int ic = k / 9, r = k - ic*9;
    int ky = r / 3, kx = r - ky*3;
    int iy = 2*oy + ky, ix = 2*ox + kx;
    if (iy <= 255 && ix <= 255)
      v = x[((size_t)img*7 + ic)*65536 + iy*256 + ix];
  }
  short hh, ll; splitbf(v, hh, ll);
  ph[t] = hh; pl_[t] = ll;
}

__global__ __launch_bounds__(256) void wt_conv_k(const void* __restrict__ w,
    short* __restrict__ dhi, short* __restrict__ dlo, const int* __restrict__ flagp)
{
  int f32 = *flagp;
  int t = blockIdx.x*256 + threadIdx.x;
  if (t >= 256*64) return;
  int oc = t >> 6, k = t & 63;
  short hi = 0, lo = 0;
  if (oc < 255 && k < 63) splitbf(ldin(w, oc*63 + k, f32), hi, lo);
  dhi[t] = hi; dlo[t] = lo;
}

// ---------------- LDS-tiled separable gauss, radius 6 ----------------
template<int VERT>
__global__ __launch_bounds__(256) void gauss2_k(const float* __restrict__ in, float* __restrict__ out)
{
  __shared__ float4 S[128][16];
  int bid = blockIdx.x;
  int chunk = bid & 3;
  int fixed = (bid >> 2) & 127;
  int img = bid >> 9;
  int tid = threadIdx.x;
  int cg = tid & 15;
  int t0 = tid >> 4;
  size_t base = ((size_t)img << 22) + chunk*64 + cg*4;

  #pragma unroll
  for (int tt = t0; tt < 128; tt += 16) {
    int pix = VERT ? ((tt << 7) | fixed) : ((fixed << 7) | tt);
    S[tt][cg] = *(const float4*)(in + base + ((size_t)pix << 8));
  }
  __syncthreads();

  #pragma unroll
  for (int tt = t0; tt < 128; tt += 16) {
    float4 c = S[tt][cg];
    float ax = GW[0]*c.x, ay = GW[0]*c.y, az = GW[0]*c.z, aw = GW[0]*c.w;
    #pragma unroll
    for (int j = 1; j <= 6; ++j) {
      float4 a = {0.f,0.f,0.f,0.f}, b = {0.f,0.f,0.f,0.f};
      if (tt - j >= 0)   a = S[tt - j][cg];
      if (tt + j <= 127) b = S[tt + j][cg];
      float w = GW[j];
      ax += w*(a.x + b.x); ay += w*(a.y + b.y);
      az += w*(a.z + b.z); aw += w*(a.w + b.w);
    }
    int pix = VERT ? ((tt << 7) | fixed) : ((fixed << 7) | tt);
    float4 r; r.x = ax; r.y = ay; r.z = az; r.w = aw;
    *(float4*)(out + base + ((size_t)pix << 8)) = r;
  }
}

// bilinear sample + gather -> cat split planes (stride 288, pad zeroed)
__global__ __launch_bounds__(256) void sample_k(const float* __restrict__ ext,
    const void* __restrict__ polar, const void* __restrict__ mask,
    const int* __restrict__ ids, const int* __restrict__ flagp,
    short* __restrict__ cath, short* __restrict__ catl)
{
  int f32 = *flagp;
  int t = blockIdx.x*256 + threadIdx.x;
  if (t >= (int)PS_CAT) return;
  int ch = t % 288;
  if (ch >= 259) { cath[t] = 0; catl[t] = 0; return; }
  int n  = (t / 288) & 3;
  int bp = t / (288*4);
  int b = bp >> 11;
  int id = ids[bp];
  int row = id >> 8, col = id & 255;
  float out;
  if (ch < 255) {
    float gx = (col + 0.5f)*(1.f/128.f) - 1.f;
    float gy = (row + 0.5f)*(1.f/128.f) - 1.f;
    float px = ((gx + 1.f)*128.f - 1.f)*0.5f;
    float py = ((gy + 1.f)*128.f - 1.f)*0.5f;
    float x0f = floorf(px), y0f = floorf(py);
    int x0 = (int)x0f, y0 = (int)y0f;
    float wx1 = px - x0f, wy1 = py - y0f;
    int img = b*4 + n;
    const float* base = ext + ((size_t)img << 22) + ch;
    float acc = 0.f;
    float w00 = (1.f-wy1)*(1.f-wx1);
    if (y0 >= 0 && y0 <= 127 && x0 >= 0 && x0 <= 127)         acc += base[(size_t)((y0<<7)+x0) << 8]*w00;
    float w01 = (1.f-wy1)*wx1;
    if (y0 >= 0 && y0 <= 127 && x0+1 >= 0 && x0+1 <= 127)     acc += base[(size_t)((y0<<7)+x0+1) << 8]*w01;
    float w10 = wy1*(1.f-wx1);
    if (y0+1 >= 0 && y0+1 <= 127 && x0 >= 0 && x0 <= 127)     acc += base[(size_t)(((y0+1)<<7)+x0) << 8]*w10;
    float w11 = wy1*wx1;
    if (y0+1 >= 0 && y0+1 <= 127 && x0+1 >= 0 && x0+1 <= 127) acc += base[(size_t)(((y0+1)<<7)+x0+1) << 8]*w11;
    out = acc;
  } else {
    int c = ch - 255;
    float iv = ldin(polar, (((size_t)(b*4+n)*4 + c)<<16) + id, f32);
    float mv = ldin(mask, (b<<16) + id, f32);
    out = iv*mv;
  }
  short hh, ll; splitbf(out, hh, ll);
  cath[t] = hh; catl[t] = ll;
}

// ---------------- weight transpose+split: Wt[N][Kp] ----------------
__global__ __launch_bounds__(256) void wt_k(const void* __restrict__ src,
    short* __restrict__ dhi, short* __restrict__ dlo,
    int K, int N, int Kp, const int* __restrict__ flagp)
{
  int f32 = *flagp;
  int t = blockIdx.x*256 + threadIdx.x;
  if (t >= N*Kp) return;
  int n = t / Kp, k = t % Kp;
  short hi = 0, lo = 0;
  if (k < K) splitbf(ldin(src, (size_t)k*N + n, f32), hi, lo);
  dhi[t] = hi; dlo[t] = lo;
}

// ---------------- bf16x3 MFMA GEMM, 128x128 tile ----------------
__global__ __launch_bounds__(256) void gemm_mfma_k(
    const short* __restrict__ Ah_g, const short* __restrict__ Al_g, int As,
    const short* __restrict__ Bh, const short* __restrict__ Bl, int Kp,
    short* __restrict__ Ch, short* __restrict__ Cl, float* __restrict__ Cf,
    int M, int K, int N, int relu,
    const void* __restrict__ bias, int biasN, const int* __restrict__ flagp)
{
  __shared__ __align__(16) short AhL[128*40];
  __shared__ __align__(16) short AlL[128*40];
  __shared__ __align__(16) short BhL[128*40];
  __shared__ __align__(16) short BlL[128*40];
  int tid = threadIdx.x;
  int lane = tid & 63, wid = tid >> 6;
  int wr = wid >> 1, wc = wid & 1;
  int l15 = lane & 15, lg = lane >> 4;
  int brow = blockIdx.y*128, bcol = blockIdx.x*128;
  int srow = tid >> 1, skc = (tid & 1)*16;
  const short* asegh = Ah_g + (size_t)(brow + srow)*As;
  const short* asegl = Al_g + (size_t)(brow + srow)*As;
  const short* bsegh = Bh + (size_t)(bcol + srow)*Kp;
  const short* bsegl = Bl + (size_t)(bcol + srow)*Kp;
  f4v acc[4][4] = {};

  for (int k0 = 0; k0 < K; k0 += 32) {
    __syncthreads();
    int gk = k0 + skc;
    *(s8v*)&AhL[srow*40 + skc]     = *(const s8v*)(asegh + gk);
    *(s8v*)&AhL[srow*40 + skc + 8] = *(const s8v*)(asegh + gk + 8);
    *(s8v*)&AlL[srow*40 + skc]     = *(const s8v*)(asegl + gk);
    *(s8v*)&AlL[srow*40 + skc + 8] = *(const s8v*)(asegl + gk + 8);
    {
      s8v h0 = 0, h1 = 0, l0 = 0, l1 = 0;
      if (gk < Kp) {
        h0 = *(const s8v*)(bsegh + gk); h1 = *(const s8v*)(bsegh + gk + 8);
        l0 = *(const s8v*)(bsegl + gk); l1 = *(const s8v*)(bsegl + gk + 8);
      }
      *(s8v*)&BhL[srow*40 + skc]     = h0;
      *(s8v*)&BhL[srow*40 + skc + 8] = h1;
      *(s8v*)&BlL[srow*40 + skc]     = l0;
      *(s8v*)&BlL[srow*40 + skc + 8] = l1;
    }
    __syncthreads();
    s8v ah[4], al[4], bh[4], bl[4];
    #pragma unroll
    for (int m = 0; m < 4; ++m) {
      ah[m] = *(const s8v*)&AhL[(wr*64 + m*16 + l15)*40 + lg*8];
      al[m] = *(const s8v*)&AlL[(wr*64 + m*16 + l15)*40 + lg*8];
    }
    #pragma unroll
    for (int n = 0; n < 4; ++n) {
      bh[n] = *(const s8v*)&BhL[(wc*64 + n*16 + l15)*40 + lg*8];
      bl[n] = *(const s8v*)&BlL[(wc*64 + n*16 + l15)*40 + lg*8];
    }
    #pragma unroll
    for (int m = 0; m < 4; ++m)
      #pragma unroll
      for (int n = 0; n < 4; ++n) {
        f4v t = acc[m][n];
        t = __builtin_amdgcn_mfma_f32_16x16x32_bf16(ah[m], bh[n], t, 0, 0, 0);
        t = __builtin_amdgcn_mfma_f32_16x16x32_bf16(al[m], bh[n], t, 0, 0, 0);
        t = __builtin_amdgcn_mfma_f32_16x16x32_bf16(ah[m], bl[n], t, 0, 0, 0);
        acc[m][n] = t;
      }
  }

  int f32 = bias ? *flagp : 0;
  #pragma unroll
  for (int m = 0; m < 4; ++m)
    #pragma unroll
    for (int n = 0; n < 4; ++n)
      #pragma unroll
      for (int r = 0; r < 4; ++r) {
        int row = brow + wr*64 + m*16 + lg*4 + r;
        int col = bcol + wc*64 + n*16 + l15;
        float v = acc[m][n][r];
        if (bias && col < biasN) v += ldin(bias, col, f32);
        if (relu) v = fmaxf(v, 0.f);
        size_t idx = (size_t)row*N + col;
        if (Cf) Cf[idx] = v;
        else { short hh, ll; splitbf(v, hh, ll); Ch[idx] = hh; Cl[idx] = ll; }
      }
}

// ---------------- bf16x3 MFMA GEMM, 64x64 tile (for narrow/short GEMMs) ----------------
__global__ __launch_bounds__(256) void gemm_mfma64_k(
    const short* __restrict__ Ah_g, const short* __restrict__ Al_g, int As,
    const short* __restrict__ Bh, const short* __restrict__ Bl, int Kp,
    short* __restrict__ Ch, short* __restrict__ Cl,
    int M, int K, int N, int relu)
{
  __shared__ __align__(16) short AhL[64*40];
  __shared__ __align__(16) short AlL[64*40];
  __shared__ __align__(16) short BhL[64*40];
  __shared__ __align__(16) short BlL[64*40];
  int tid = threadIdx.x;
  int lane = tid & 63, wid = tid >> 6;
  int wr = wid >> 1, wc = wid & 1;
  int l15 = lane & 15, lg = lane >> 4;
  int brow = blockIdx.y*64, bcol = blockIdx.x*64;
  int srow = tid >> 2, skc = (tid & 3)*8;
  const short* asegh = Ah_g + (size_t)(brow + srow)*As;
  const short* asegl = Al_g + (size_t)(brow + srow)*As;
  const short* bsegh = Bh + (size_t)(bcol + srow)*Kp;
  const short* bsegl = Bl + (size_t)(bcol + srow)*Kp;
  f4v acc[2][2] = {};

  for (int k0 = 0; k0 < K; k0 += 32) {
    __syncthreads();
    int gk = k0 + skc;
    *(s8v*)&AhL[srow*40 + skc] = *(const s8v*)(asegh + gk);
    *(s8v*)&AlL[srow*40 + skc] = *(const s8v*)(asegl + gk);
    {
      s8v h0 = 0, l0 = 0;
      if (gk < Kp) { h0 = *(const s8v*)(bsegh + gk); l0 = *(const s8v*)(bsegl + gk); }
      *(s8v*)&BhL[srow*40 + skc] = h0;
      *(s8v*)&BlL[srow*40 + skc] = l0;
    }
    __syncthreads();
    s8v ah[2], al[2], bh[2], bl[2];
    #pragma unroll
    for (int m = 0; m < 2; ++m) {
      ah[m] = *(const s8v*)&AhL[(wr*32 + m*16 + l15)*40 + lg*8];
      al[m] = *(const s8v*)&AlL[(wr*32 + m*16 + l15)*40 + lg*8];
    }
    #pragma unroll
    for (int n = 0; n < 2; ++n) {
      bh[n] = *(const s8v*)&BhL[(wc*32 + n*16 + l15)*40 + lg*8];
      bl[n] = *(const s8v*)&BlL[(wc*32 + n*16 + l15)*40 + lg*8];
    }
    #pragma unroll
    for (int m = 0; m < 2; ++m)
      #pragma unroll
      for (int n = 0; n < 2; ++n) {
        f4v t = acc[m][n];
        t = __builtin_amdgcn_mfma_f32_16x16x32_bf16(ah[m], bh[n], t, 0, 0, 0);
        t = __builtin_amdgcn_mfma_f32_16x16x32_bf16(al[m], bh[n], t, 0, 0, 0);
        t = __builtin_amdgcn_mfma_f32_16x16x32_bf16(ah[m], bl[n], t, 0, 0, 0);
        acc[m][n] = t;
      }
  }

  #pragma unroll
  for (int m = 0; m < 2; ++m)
    #pragma unroll
    for (int n = 0; n < 2; ++n)
      #pragma unroll
      for (int r = 0; r < 4; ++r) {
        int row = brow + wr*32 + m*16 + lg*4 + r;
        int col = bcol + wc*32 + n*16 + l15;
        float v = acc[m][n][r];
        if (relu) v = fmaxf(v, 0.f);
        size_t idx = (size_t)row*N + col;
        short hh, ll; splitbf(v, hh, ll);
        Ch[idx] = hh; Cl[idx] = ll;
      }
}

// ---------------- LayerNorm on split planes ----------------
__global__ __launch_bounds__(256) void ln_k(const short* __restrict__ xh,
    const short* __restrict__ xl, const short* __restrict__ rh, const short* __restrict__ rl,
    const void* __restrict__ g, const void* __restrict__ bta,
    short* __restrict__ oh, short* __restrict__ ol, int D, const int* __restrict__ flagp)
{
  int f32 = *flagp;
  int row = blockIdx.x;
  size_t base = (size_t)row*D;
  float s = 0.f, s2 = 0.f;
  for (int i = threadIdx.x; i < D; i += 256) {
    float v = bs2f(xh[base+i]) + bs2f(xl[base+i]) + bs2f(rh[base+i]) + bs2f(rl[base+i]);
    s += v; s2 += v*v;
  }
  #pragma unroll
  for (int o = 32; o; o >>= 1) { s += __shfl_down(s, o); s2 += __shfl_down(s2, o); }
  __shared__ float as_[4], as2[4];
  __shared__ float mean_s, inv_s;
  int wv = threadIdx.x >> 6;
  if ((threadIdx.x & 63) == 0) { as_[wv] = s; as2[wv] = s2; }
  __syncthreads();
  if (threadIdx.x == 0) {
    float S = as_[0]+as_[1]+as_[2]+as_[3];
    float S2 = as2[0]+as2[1]+as2[2]+as2[3];
    float m = S / (float)D;
    float var = S2/(float)D - m*m;
    mean_s = m; inv_s = rsqrtf(var + 1e-5f);
  }
  __syncthreads();
  float m = mean_s, inv = inv_s;
  for (int i = threadIdx.x; i < D; i += 256) {
    float v = bs2f(xh[base+i]) + bs2f(xl[base+i]) + bs2f(rh[base+i]) + bs2f(rl[base+i]);
    float res = (v - m)*inv*ldin(g, i, f32) + ldin(bta, i, f32);
    short hh, ll; splitbf(res, hh, ll);
    oh[base+i] = hh; ol[base+i] = ll;
  }
}

// ---------------- ia attention (T=4) on split planes ----------------
__global__ __launch_bounds__(256) void attn_small_k(const short* __restrict__ qh,
    const short* __restrict__ ql, short* __restrict__ oh, short* __restrict__ ol)
{
  int t = blockIdx.x*256 + threadIdx.x;
  if (t >= BP_*8*4) return;
  int qn = t & 3, h = (t >> 2) & 7, bp = t >> 5;
  size_t base = (size_t)bp*4*768;
  size_t qoff = base + qn*768 + h*32;
  float qv[32];
  #pragma unroll
  for (int i = 0; i < 32; ++i) qv[i] = bs2f(qh[qoff+i]) + bs2f(ql[qoff+i]);
  float s[4]; float mx = -1e30f;
  #pragma unroll
  for (int kn = 0; kn < 4; ++kn) {
    size_t koff = base + kn*768 + 256 + h*32;
    float d = 0.f;
    #pragma unroll
    for (int i = 0; i < 32; ++i) d += qv[i]*(bs2f(qh[koff+i]) + bs2f(ql[koff+i]));
    s[kn] = d * 0.17677669529663687f;
    mx = fmaxf(mx, s[kn]);
  }
  float sum = 0.f;
  #pragma unroll
  for (int kn = 0; kn < 4; ++kn) { s[kn] = expf(s[kn]-mx); sum += s[kn]; }
  float inv = 1.f/sum;
  size_t obase = (size_t)(bp*4 + qn)*256 + h*32;
  #pragma unroll
  for (int i = 0; i < 32; ++i) {
    float acc = 0.f;
    #pragma unroll
    for (int kn = 0; kn < 4; ++kn) {
      size_t voff = base + kn*768 + 512 + h*32 + i;
      acc += s[kn]*(bs2f(qh[voff]) + bs2f(ql[voff]));
    }
    short hh, ll; splitbf(acc*inv, hh, ll);
    oh[obase+i] = hh; ol[obase+i] = ll;
  }
}

__global__ __launch_bounds__(256) void enh_pos_k(const short* __restrict__ ph,
    const short* __restrict__ pl_, const int* __restrict__ ids,
    const void* __restrict__ pa_pos, short* __restrict__ zh, short* __restrict__ zl,
    const int* __restrict__ flagp)
{
  int f32 = *flagp;
  int t = blockIdx.x*256 + threadIdx.x;
  if (t >= BP_*384) return;
  int f = t % 384, bp = t / 384;
  size_t pb = (size_t)bp*4*384 + f;
  float v0 = bs2f(ph[pb])       + bs2f(pl_[pb]);
  float v1 = bs2f(ph[pb+384])   + bs2f(pl_[pb+384]);
  float v2 = bs2f(ph[pb+768])   + bs2f(pl_[pb+768]);
  float v3 = bs2f(ph[pb+1152])  + bs2f(pl_[pb+1152]);
  float m = fmaxf(fmaxf(v0, v1), fmaxf(v2, v3));
  int id = ids[bp];
  int row = id >> 8, col = id & 255;
  float gx = (col + 0.5f)*(1.f/128.f) - 1.f;
  float gy = (row + 0.5f)*(1.f/128.f) - 1.f;
  float res = m + gx*ldin(pa_pos, f, f32) + gy*ldin(pa_pos, 384 + f, f32);
  short hh, ll; splitbf(res, hh, ll);
  zh[t] = hh; zl[t] = ll;
}

// ---------------- global V transpose: qkvp planes -> VT[b][h][48][2048] hi/lo ----------------
__global__ __launch_bounds__(256) void vtr_k(const short* __restrict__ qh,
    const short* __restrict__ ql, short* __restrict__ vth, short* __restrict__ vtl)
{
  __shared__ short Th[128*58], Tl[128*58];
  int bid = blockIdx.x;
  int kt = bid & 15;        // kv tile of 128
  int h  = (bid >> 4) & 7;
  int b  = bid >> 7;
  int tid = threadIdx.x;
  int kv0 = kt*128;
  {
    int kv = tid >> 1, hf = tid & 1;
    const short* sh = qh + ((size_t)(b*2048 + kv0 + kv))*1152 + 768 + h*48 + hf*24;
    const short* sl = ql + ((size_t)(b*2048 + kv0 + kv))*1152 + 768 + h*48 + hf*24;
    short vh[24], vl[24];
    #pragma unroll
    for (int j = 0; j < 24; j += 8) {
      *(s8v*)&vh[j] = *(const s8v*)(sh + j);
      *(s8v*)&vl[j] = *(const s8v*)(sl + j);
    }
    #pragma unroll
    for (int j = 0; j < 24; ++j) {
      Th[kv*58 + hf*24 + j] = vh[j];
      Tl[kv*58 + hf*24 + j] = vl[j];
    }
  }
  __syncthreads();
  for (int idx = tid; idx < 384; idx += 256) {
    int d = idx >> 3, ch = idx & 7;      // ch: chunk of 16 kv
    short oh[16], olv[16];
    #pragma unroll
    for (int j = 0; j < 16; ++j) {
      int kv = ch*16 + j;
      oh[j]  = Th[kv*58 + d];
      olv[j] = Tl[kv*58 + d];
    }
    size_t dst = ((size_t)((b*8 + h)*48 + d))*2048 + kv0 + ch*16;
    *(s8v*)(vth + dst)     = *(s8v*)&oh[0];
    *(s8v*)(vth + dst + 8) = *(s8v*)&oh[8];
    *(s8v*)(vtl + dst)     = *(s8v*)&olv[0];
    *(s8v*)(vtl + dst + 8) = *(s8v*)&olv[8];
  }
}

// ---------------- pa attention v4: flash bf16x3, KVBLK=64, LDS-staged, global VT ----------------
__global__ __launch_bounds__(256) void attn_big4_k(const short* __restrict__ qh,
    const short* __restrict__ ql, const short* __restrict__ vth, const short* __restrict__ vtl,
    float* __restrict__ po, float* __restrict__ pm, float* __restrict__ pl)
{
  __shared__ __align__(16) short KSh[64*72], KSl[64*72];
  __shared__ __align__(16) short VTh[48*72], VTl[48*72];
  __shared__ __align__(16) short PSh[4][16*72], PSl[4][16*72];
  int bid = blockIdx.x;
  int sp = bid % SPLITS;
  int rem = bid / SPLITS;
  int qt = rem & 31;
  int h  = (rem >> 5) & 7;
  int b  = rem >> 8;
  int tid = threadIdx.x, lane = tid & 63, w = tid >> 6;
  int l15 = lane & 15, lg = lane >> 4;

  s8v qfh[2], qfl[2];
  {
    int q = qt*64 + w*16 + l15;
    const short* bh = qh + ((size_t)(b*2048 + q))*1152 + h*48;
    const short* bl = ql + ((size_t)(b*2048 + q))*1152 + h*48;
    #pragma unroll
    for (int ks = 0; ks < 2; ++ks) {
      int d0 = ks*32 + lg*8;
      if (d0 < 48) { qfh[ks] = *(const s8v*)(bh + d0); qfl[ks] = *(const s8v*)(bl + d0); }
      else         { qfh[ks] = 0; qfl[ks] = 0; }
    }
  }
  // zero K pad region d=48..63 once (64 kv rows x 16 d x 2 planes)
  for (int idx = tid; idx < 2048; idx += 256) {
    int hl = idx >> 10, j = idx & 1023;
    int kv = j >> 4, dd = 48 + (j & 15);
    short* dst = hl ? KSl : KSh;
    dst[kv*72 + dd] = 0;
  }

  f4v oacc[3] = {};
  float mrun[4] = {-1e30f, -1e30f, -1e30f, -1e30f};
  float lrun[4] = {0.f, 0.f, 0.f, 0.f};
  const float scale = 0.14433756729740643f;
  int kvbase = sp*(2048/SPLITS);
  const short* vthb = vth + ((size_t)(b*8 + h)*48)*2048;
  const short* vtlb = vtl + ((size_t)(b*8 + h)*48)*2048;

  for (int kt = 0; kt < 2048/SPLITS/64; ++kt) {
    __syncthreads();
    int kv0 = kvbase + kt*64;
    // stage K tile: 64 rows x 48 d, hi+lo (vector copies)
    for (int idx = tid; idx < 768; idx += 256) {
      int hl = idx >= 384; int j = hl ? idx - 384 : idx;
      int kv = j / 6, seg = j % 6;
      const short* src = (hl ? ql : qh) + ((size_t)(b*2048 + kv0 + kv))*1152 + 384 + h*48 + seg*8;
      short* dst = hl ? KSl : KSh;
      *(s8v*)&dst[kv*72 + seg*8] = *(const s8v*)src;
    }
    // stage V^T tile: 48 d x 64 kv, hi+lo from global VT (vector copies)
    for (int idx = tid; idx < 384; idx += 256) {
      int hl = idx >= 192; int j = hl ? idx - 192 : idx;
      int d = j >> 2, sg = j & 3;
      const short* src = (hl ? vtlb : vthb) + (size_t)d*2048 + kv0 + sg*16;
      short* dst = hl ? VTl : VTh;
      *(s8v*)&dst[d*72 + sg*16]     = *(const s8v*)src;
      *(s8v*)&dst[d*72 + sg*16 + 8] = *(const s8v*)(src + 8);
    }
    __syncthreads();

    // S = Q K^T over 64 kv (4 col-blocks)
    f4v s[4];
    #pragma unroll
    for (int nb = 0; nb < 4; ++nb) {
      f4v t = {};
      #pragma unroll
      for (int ks = 0; ks < 2; ++ks) {
        s8v kh = *(const s8v*)&KSh[(nb*16 + l15)*72 + ks*32 + lg*8];
        s8v kl = *(const s8v*)&KSl[(nb*16 + l15)*72 + ks*32 + lg*8];
        t = __builtin_amdgcn_mfma_f32_16x16x32_bf16(qfh[ks], kh, t, 0, 0, 0);
        t = __builtin_amdgcn_mfma_f32_16x16x32_bf16(qfl[ks], kh, t, 0, 0, 0);
        t = __builtin_amdgcn_mfma_f32_16x16x32_bf16(qfh[ks], kl, t, 0, 0, 0);
      }
      s[nb] = t * scale;
    }
    // online softmax: lane holds rows lg*4+r, cols nb*16+l15
    float mnew[4], alpha[4], rsum[4];
    #pragma unroll
    for (int r = 0; r < 4; ++r) {
      float pmx = fmaxf(fmaxf(s[0][r], s[1][r]), fmaxf(s[2][r], s[3][r]));
      #pragma unroll
      for (int off = 1; off < 16; off <<= 1) pmx = fmaxf(pmx, __shfl_xor(pmx, off));
      mnew[r] = fmaxf(mrun[r], pmx);
      alpha[r] = __expf(mrun[r] - mnew[r]);
      rsum[r] = 0.f;
    }
    #pragma unroll
    for (int nb = 0; nb < 4; ++nb)
      #pragma unroll
      for (int r = 0; r < 4; ++r) {
        float p = __expf(s[nb][r] - mnew[r]);
        s[nb][r] = p;
        rsum[r] += p;
      }
    #pragma unroll
    for (int r = 0; r < 4; ++r) {
      float rs = rsum[r];
      #pragma unroll
      for (int off = 1; off < 16; off <<= 1) rs += __shfl_xor(rs, off);
      lrun[r] = lrun[r]*alpha[r] + rs;
      mrun[r] = mnew[r];
    }
    // P split -> per-wave LDS [16 q][64 kv], stride 72
    #pragma unroll
    for (int nb = 0; nb < 4; ++nb)
      #pragma unroll
      for (int r = 0; r < 4; ++r) {
        short hh, ll; splitbf(s[nb][r], hh, ll);
        PSh[w][(lg*4 + r)*72 + nb*16 + l15] = hh;
        PSl[w][(lg*4 + r)*72 + nb*16 + l15] = ll;
      }
    // rescale O
    #pragma unroll
    for (int db = 0; db < 3; ++db)
      #pragma unroll
      for (int r = 0; r < 4; ++r)
        oacc[db][r] *= alpha[r];
    // O += P V over kv=64 (two 32-slots)
    s8v pf_h[2], pf_l[2];
    #pragma unroll
    for (int ks = 0; ks < 2; ++ks) {
      pf_h[ks] = *(const s8v*)&PSh[w][l15*72 + ks*32 + lg*8];
      pf_l[ks] = *(const s8v*)&PSl[w][l15*72 + ks*32 + lg*8];
    }
    #pragma unroll
    for (int db = 0; db < 3; ++db) {
      f4v t = oacc[db];
      #pragma unroll
      for (int ks = 0; ks < 2; ++ks) {
        s8v vh = *(const s8v*)&VTh[(db*16 + l15)*72 + ks*32 + lg*8];
        s8v vl = *(const s8v*)&VTl[(db*16 + l15)*72 + ks*32 + lg*8];
        t = __builtin_amdgcn_mfma_f32_16x16x32_bf16(pf_h[ks], vh, t, 0, 0, 0);
        t = __builtin_amdgcn_mfma_f32_16x16x32_bf16(pf_l[ks], vh, t, 0, 0, 0);
        t = __builtin_amdgcn_mfma_f32_16x16x32_bf16(pf_h[ks], vl, t, 0, 0, 0);
      }
      oacc[db] = t;
    }
  }

  #pragma unroll
  for (int db = 0; db < 3; ++db)
    #pragma unroll
    for (int r = 0; r < 4; ++r) {
      int q = qt*64 + w*16 + lg*4 + r;
      po[((size_t)(sp*BP_ + b*2048 + q))*384 + h*48 + db*16 + l15] = oacc[db][r];
    }
  if (l15 == 0) {
    #pragma unroll
    for (int r = 0; r < 4; ++r) {
      int q = qt*64 + w*16 + lg*4 + r;
      pm[((size_t)(sp*BP_ + b*2048 + q))*8 + h] = mrun[r];
      pl[((size_t)(sp*BP_ + b*2048 + q))*8 + h] = lrun[r];
    }
  }
}

// merge SPLITS partials (exact logsumexp combine)
__global__ __launch_bounds__(256) void attn_merge_k(const float* __restrict__ po,
    const float* __restrict__ pm, const float* __restrict__ pl,
    short* __restrict__ oh, short* __restrict__ ol)
{
  int t = blockIdx.x*256 + threadIdx.x;
  if (t >= BP_*384) return;
  int bp = t / 384, f = t - bp*384;
  int h = f / 48;
  float M = -1e30f;
  #pragma unroll
  for (int sp = 0; sp < SPLITS; ++sp)
    M = fmaxf(M, pm[((size_t)(sp*BP_ + bp))*8 + h]);
  float num = 0.f, den = 0.f;
  #pragma unroll
  for (int sp = 0; sp < SPLITS; ++sp) {
    float wgt = __expf(pm[((size_t)(sp*BP_ + bp))*8 + h] - M);
    num += po[((size_t)(sp*BP_ + bp))*384 + f]*wgt;
    den += pl[((size_t)(sp*BP_ + bp))*8 + h]*wgt;
  }
  float res = num/den;
  short hh, ll; splitbf(res, hh, ll);
  oh[t] = hh; ol[t] = ll;
}

// ---------------- heads: one wave per bp row, coalesced + shuffle reduce ----------------
__global__ __launch_bounds__(256) void heads_k(const short* __restrict__ gh,
    const short* __restrict__ gl, const void* __restrict__ hn, const void* __restrict__ hp,
    float* __restrict__ raw5, const int* __restrict__ flagp)
{
  int f32 = *flagp;
  int gtid = blockIdx.x*256 + threadIdx.x;
  int bp = gtid >> 6;
  if (bp >= BP_) return;
  int lane = gtid & 63;
  size_t base = (size_t)bp*384;
  float n0=0,n1=0,n2=0,p0=0,p1=0;
  #pragma unroll
  for (int it = 0; it < 6; ++it) {
    int k = lane + it*64;
    float gv = bs2f(gh[base+k]) + bs2f(gl[base+k]);
    n0 += gv*ldin(hn, k*3+0, f32);
    n1 += gv*ldin(hn, k*3+1, f32);
    n2 += gv*ldin(hn, k*3+2, f32);
    p0 += gv*ldin(hp, k*2+0, f32);
    p1 += gv*ldin(hp, k*2+1, f32);
  }
  #pragma unroll
  for (int off = 32; off; off >>= 1) {
    n0 += __shfl_down(n0, off);
    n1 += __shfl_down(n1, off);
    n2 += __shfl_down(n2, off);
    p0 += __shfl_down(p0, off);
    p1 += __shfl_down(p1, off);
  }
  if (lane == 0) {
    raw5[bp*5+0]=n0; raw5[bp*5+1]=n1; raw5[bp*5+2]=n2;
    raw5[bp*5+3]=p0; raw5[bp*5+4]=p1;
  }
}

__global__ __launch_bounds__(256) void zero_out_k(void* __restrict__ out, int n,
    const int* __restrict__ flagp)
{
  int f32 = *flagp;
  int t = blockIdx.x*256 + threadIdx.x;
  if (t < n) stout(out, t, 0.f, f32);
}

__global__ __launch_bounds__(256) void wm_init_k(int* __restrict__ wm)
{
  int t = blockIdx.x*256 + threadIdx.x;
  if (t < 2*65536) wm[t] = -1;
}

__global__ __launch_bounds__(256) void wm_mark_k(const int* __restrict__ ids, int* __restrict__ wm)
{
  int t = blockIdx.x*256 + threadIdx.x;
  if (t >= BP_) return;
  int b = t >> 11, p = t & 2047;
  atomicMax(&wm[(b<<16) + ids[t]], p);
}

__global__ __launch_bounds__(256) void scatter_k(const int* __restrict__ ids,
    const int* __restrict__ wm, const float* __restrict__ raw5, void* __restrict__ out,
    const int* __restrict__ flagp)
{
  int f32 = *flagp;
  int t = blockIdx.x*256 + threadIdx.x;
  if (t >= BP_) return;
  int b = t >> 11, p = t & 2047;
  int id = ids[t];
  if (wm[(b<<16) + id] != p) return;
  float n0 = raw5[t*5+0], n1 = raw5[t*5+1], n2 = raw5[t*5+2];
  float inv = 1.f / fmaxf(sqrtf(n0*n0 + n1*n1 + n2*n2), 1e-12f);
  stout(out, ((size_t)(b*3+0)<<16) + id, n0*inv, f32);
  stout(out, ((size_t)(b*3+1)<<16) + id, n1*inv, f32);
  stout(out, ((size_t)(b*3+2)<<16) + id, n2*inv, f32);
  size_t matoff = (size_t)B_*3*65536;
  stout(out, matoff + ((size_t)(b*2+0)<<16) + id, raw5[t*5+3], f32);
  stout(out, matoff + ((size_t)(b*2+1)<<16) + id, raw5[t*5+4], f32);
}

// ---------------- host ----------------
extern "C" void kernel_launch(void* const* d_in, const int* in_sizes, int n_in,
                              void* d_out, int out_size, void* d_ws, size_t ws_size,
                              hipStream_t stream)
{
  const void* polar   = d_in[0];
  const void* mask    = d_in[1];
  const void* pprop   = d_in[2];
  const void* conv_w  = d_in[3];
  const void* conv_b  = d_in[4];
  const void* ia_win  = d_in[5];
  const void* ia_qkv  = d_in[6];
  const void* ia_out  = d_in[7];
  const void* ia_ln1g = d_in[8];
  const void* ia_ln1b = d_in[9];
  const void* ia_ff1  = d_in[10];
  const void* ia_ff2  = d_in[11];
  const void* ia_ln2g = d_in[12];
  const void* ia_ln2b = d_in[13];
  const void* ia_proj = d_in[14];
  const void* pa_pos  = d_in[15];
  const void* pa_qkv  = d_in[16];
  const void* pa_out  = d_in[17];
  const void* pa_ln1g = d_in[18];
  const void* pa_ln1b = d_in[19];
  const void* pa_ff1  = d_in[20];
  const void* pa_ff2  = d_in[21];
  const void* pa_ln2g = d_in[22];
  const void* pa_ln2b = d_in[23];
  const void* head_n  = d_in[24];
  const void* head_p  = d_in[25];
  const int*  ids     = (const int*)d_in[26];

  float* ws = nullptr;
  hipGetSymbolAddress((void**)&ws, HIP_SYMBOL(g_scratch));

  float* xbuf   = ws + OFF_X;
  float* extA   = ws + OFF_EXTA;
  float* extB   = ws + OFF_EXTB;
  short* path    = (short*)(ws + OFF_EXTB);  short* patl    = path    + PS_PAT;
  short* cath    = (short*)(ws + OFF_CAT);   short* catl    = cath    + PS_CAT;
  short* tokh    = (short*)(ws + OFF_TOK);   short* tokl    = tokh    + PS_256;
  short* qkvh    = (short*)(ws + OFF_QKV);   short* qkvl    = qkvh    + PS_QKV;
  short* attnoh  = (short*)(ws + OFF_ATTNO); short* attnol  = attnoh  + PS_256;
  short* tmp256h = (short*)(ws + OFF_TMP256);short* tmp256l = tmp256h + PS_256;
  short* y1h     = (short*)(ws + OFF_Y1);    short* y1l     = y1h     + PS_256;
  short* ffh     = (short*)(ws + OFF_FF);    short* ffl     = ffh     + PS_FF;
  short* tmp256bh= (short*)(ws + OFF_TMP256B);short* tmp256bl= tmp256bh + PS_256;
  short* y2h     = (short*)(ws + OFF_Y2);    short* y2l     = y2h     + PS_256;
  short* projh   = (short*)(ws + OFF_PROJ);  short* projl   = projh   + PS_PROJ;
  short* zh      = (short*)(ws + OFF_Z);     short* zl      = zh      + PS_384;
  short* qkvph   = (short*)(ws + OFF_QKVP);  short* qkvpl   = qkvph   + PS_QKVP;
  short* attnph  = (short*)(ws + OFF_ATTNP); short* attnpl  = attnph  + PS_384;
  short* tmp384h = (short*)(ws + OFF_TMP384);short* tmp384l = tmp384h + PS_384;
  short* z2h     = (short*)(ws + OFF_Z2);    short* z2l     = z2h     + PS_384;
  short* ffb2h   = (short*)(ws + OFF_FFB2);  short* ffb2l   = ffb2h   + PS_FF2;
  short* tmp384bh= (short*)(ws + OFF_TMP384B);short* tmp384bl= tmp384bh + PS_384;
  short* glbh    = (short*)(ws + OFF_GLB);   short* glbl    = glbh    + PS_384;
  float* raw5   = ws + OFF_RAW5;
  int*   wm     = (int*)(ws + OFF_WM);
  int*   flagp  = (int*)(ws + OFF_FLAG);
  short* wtb    = (short*)(ws + OFF_WTB);
  short* wtb_lo = wtb + WT_LO_OFF;
  float* pobuf  = ws + OFF_PO;
  float* pmbuf  = ws + OFF_PM;
  float* plbuf  = ws + OFF_PL;
  short* vth    = (short*)(ws + OFF_VT);
  short* vtl    = vth + PS_VT;

  probe_k<<<1, 64, 0, stream>>>((const unsigned int*)mask, flagp);

  struct WDesc { const void* src; int K, N, Kp; size_t off; };
  size_t woff = 0;
  auto pad16 = [](int k){ return (k + 15) & ~15; };
  WDesc wd[10];
  const void* srcs[10] = {ia_win, ia_qkv, ia_out, ia_ff1, ia_ff2, ia_proj, pa_qkv, pa_out, pa_ff1, pa_ff2};
  int Ks[10]   = {259, 256, 256, 256, 1024, 256, 384, 384, 384, 1024};
  int Ns[10]   = {256, 768, 256, 1024, 256, 384, 1152, 384, 1024, 384};
  for (int i = 0; i < 10; ++i) {
    wd[i] = {srcs[i], Ks[i], Ns[i], pad16(Ks[i]), woff};
    woff += (size_t)wd[i].N * wd[i].Kp;
    int tot = wd[i].N * wd[i].Kp;
    wt_k<<<(tot + 255)/256, 256, 0, stream>>>(wd[i].src, wtb + wd[i].off, wtb_lo + wd[i].off,
                                              wd[i].K, wd[i].N, wd[i].Kp, flagp);
  }
  wt_conv_k<<<(256*64)/256, 256, 0, stream>>>(conv_w, wtb + WT_CONV_HI, wtb + WT_CONV_LO, flagp);

  int use64[10] = {1, 0, 1, 0, 1, 1, 1, 1, 1, 1};
  auto gemm = [&](const short* Ahp, const short* Alp, int As, int wi,
                  short* Chp, short* Clp, int M, int relu) {
    if (use64[wi]) {
      dim3 bl(256), gr(wd[wi].N/64, M/64);
      gemm_mfma64_k<<<gr, bl, 0, stream>>>(Ahp, Alp, As, wtb + wd[wi].off, wtb_lo + wd[wi].off,
                                           wd[wi].Kp, Chp, Clp, M, wd[wi].K, wd[wi].N, relu);
    } else {
      dim3 bl(256), gr(wd[wi].N/128, M/128);
      gemm_mfma_k<<<gr, bl, 0, stream>>>(Ahp, Alp, As, wtb + wd[wi].off, wtb_lo + wd[wi].off,
                                         wd[wi].Kp, Chp, Clp, nullptr,
                                         M, wd[wi].K, wd[wi].N, relu, nullptr, 0, flagp);
    }
  };

  // stage 1: build, im2col(split), conv-as-GEMM (fp32 out), LDS gauss
  build_x_k<<<(int)((SZ_X+255)/256), 256, 0, stream>>>(polar, mask, pprop, flagp, xbuf);
  im2col_k<<<(int)((PS_PAT+255)/256), 256, 0, stream>>>(xbuf, path, patl);
  {
    dim3 bl(256), gr(256/128, CONV_M/128);
    gemm_mfma_k<<<gr, bl, 0, stream>>>(path, patl, 64, wtb + WT_CONV_HI, wtb + WT_CONV_LO, 64,
                                       nullptr, nullptr, extA,
                                       CONV_M, 64, 256, 1, conv_b, 255, flagp);
  }
  gauss2_k<1><<<8*128*4, 256, 0, stream>>>(extA, extB);
  gauss2_k<0><<<8*128*4, 256, 0, stream>>>(extB, extA);

  // stage 2
  sample_k<<<(int)((PS_CAT+255)/256), 256, 0, stream>>>(extA, polar, mask, ids, flagp, cath, catl);
  gemm(cath, catl, 288, 0, tokh, tokl, ROWS_IA, 0);

  // stage 3: ia transformer (T=4)
  gemm(tokh, tokl, 256, 1, qkvh, qkvl, ROWS_IA, 0);
  attn_small_k<<<(BP_*8*4)/256, 256, 0, stream>>>(qkvh, qkvl, attnoh, attnol);
  gemm(attnoh, attnol, 256, 2, tmp256h, tmp256l, ROWS_IA, 0);
  ln_k<<<ROWS_IA, 256, 0, stream>>>(tmp256h, tmp256l, tokh, tokl, ia_ln1g, ia_ln1b, y1h, y1l, 256, flagp);
  gemm(y1h, y1l, 256, 3, ffh, ffl, ROWS_IA, 1);
  gemm(ffh, ffl, 1024, 4, tmp256bh, tmp256bl, ROWS_IA, 0);
  ln_k<<<ROWS_IA, 256, 0, stream>>>(tmp256bh, tmp256bl, y1h, y1l, ia_ln2g, ia_ln2b, y2h, y2l, 256, flagp);

  // stage 4
  gemm(y2h, y2l, 256, 5, projh, projl, ROWS_IA, 0);
  enh_pos_k<<<(BP_*384)/256, 256, 0, stream>>>(projh, projl, ids, pa_pos, zh, zl, flagp);

  // stage 5: pa transformer (T=2048)
  gemm(zh, zl, 384, 6, qkvph, qkvpl, BP_, 0);
  vtr_k<<<B_*8*16, 256, 0, stream>>>(qkvph, qkvpl, vth, vtl);
  attn_big4_k<<<B_*8*32*SPLITS, 256, 0, stream>>>(qkvph, qkvpl, vth, vtl, pobuf, pmbuf, plbuf);
  attn_merge_k<<<(BP_*384)/256, 256, 0, stream>>>(pobuf, pmbuf, plbuf, attnph, attnpl);
  gemm(attnph, attnpl, 384, 7, tmp384h, tmp384l, BP_, 0);
  ln_k<<<BP_, 256, 0, stream>>>(tmp384h, tmp384l, zh, zl, pa_ln1g, pa_ln1b, z2h, z2l, 384, flagp);
  gemm(z2h, z2l, 384, 8, ffb2h, ffb2l, BP_, 1);
  gemm(ffb2h, ffb2l, 1024, 9, tmp384bh, tmp384bl, BP_, 0);
  ln_k<<<BP_, 256, 0, stream>>>(tmp384bh, tmp384bl, z2h, z2l, pa_ln2g, pa_ln2b, glbh, glbl, 384, flagp);

  // stage 6
  heads_k<<<(BP_*64 + 255)/256, 256, 0, stream>>>(glbh, glbl, head_n, head_p, raw5, flagp);
  zero_out_k<<<(out_size+255)/256, 256, 0, stream>>>(d_out, out_size, flagp);
  wm_init_k<<<(2*65536)/256, 256, 0, stream>>>(wm);
  wm_mark_k<<<(BP_+255)/256, 256, 0, stream>>>(ids, wm);
  scatter_k<<<(BP_+255)/256, 256, 0, stream>>>(ids, wm, raw5, d_out, flagp);
}